// Round 2
// 2042.292 us; speedup vs baseline: 1.2810x; 1.2810x over previous
//
#include <hip/hip_runtime.h>
#include <hip/hip_bf16.h>

// DeformableTransformerDecoderLayer on MI355X — Round 5 (resubmit; R5 bench
// hit an infra failure, no counters). R4: 2616 us, self-attn ~1100 us with
// 0.17% HBM and 40% VALU -> stalled on uncoalesced K reads (64 lines per
// wave-load). This round: transpose K into [(b,h,d)][ki] layout (B5 scratch,
// dead at both attn points) so QK reads are coalesced short4 loads; PV
// vectorized 4-wide in d. Everything else unchanged.
//   E=256 NH=8 HD=32 NL=4 NP=4 DFFN=1024, nq=900 bs=8 Ls=100 Lv=21760.
//
// Arena (byte offsets), S = 7200*256 = 1,843,200 elems:
//   T5 f32 [S]        @ 0           running tgt (f32 accumulator)
//   B1 bf16 [S]       @ 7,372,800   q=tgt(+pos) | deform samp
//   B2 bf16 [2S]      @ 11,059,200  self QK | cross q | val(spans B3) | FFN hidden
//   B3 bf16 [S+64K]   @ 18,432,000  self V | cross KV | val tail
//   B4 bf16 [S]       @ 22,249,472  attn out | deform off
//   B5 bf16 [S]       @ 25,935,872  KT scratch | proj out | deform awl
//   FLAG int          @ 29,622,272  detected input dtype (1=f32, 0=bf16)
// NEEDED = 29,622,528 bytes.

typedef __hip_bfloat16 bf16;
typedef __attribute__((ext_vector_type(8))) short short8;
typedef __attribute__((ext_vector_type(4))) float f32x4;

__device__ __forceinline__ float toF(bf16 x) { return __bfloat162float(x); }

// bf16 (as raw short) -> f32 via exponent shift.
__device__ __forceinline__ float b2f(short v) {
    return __uint_as_float(((unsigned)(unsigned short)v) << 16);
}

__device__ __forceinline__ float ldF(const void* p, size_t i, int f32mode) {
    if (f32mode) return ((const float*)p)[i];
    return __bfloat162float(((const bf16*)p)[i]);
}
__device__ __forceinline__ void stF(void* p, size_t i, int f32mode, float v) {
    if (f32mode) ((float*)p)[i] = v;
    else ((bf16*)p)[i] = __float2bfloat16(v);
}
// mode codes: 0 = bf16 (ws), 1 = f32 (ws), 2 = external (use flag)
__device__ __forceinline__ int decode(int code, int fl) { return code == 2 ? fl : code; }

__device__ __forceinline__ short f2b(float x) {
    bf16 h = __float2bfloat16(x);
    return *(short*)&h;
}

// Load 8 consecutive elements starting at element idx as a bf16x8 fragment.
// idx is 8-element aligned. f32 path: 2x float4 + 8 converts.
__device__ __forceinline__ short8 loadFrag8(const void* p, size_t idx, int f32m) {
    short8 r;
    if (f32m) {
        const float4* q = (const float4*)((const float*)p + idx);
        float4 u = q[0];
        float4 v = q[1];
        r[0] = f2b(u.x); r[1] = f2b(u.y); r[2] = f2b(u.z); r[3] = f2b(u.w);
        r[4] = f2b(v.x); r[5] = f2b(v.y); r[6] = f2b(v.z); r[7] = f2b(v.w);
    } else {
        r = *(const short8*)((const bf16*)p + idx);
    }
    return r;
}

// ---------------------------------------------------------------------------
// Input dtype detector (unchanged).
// ---------------------------------------------------------------------------
__global__ __launch_bounds__(256) void detect_kernel(
    const unsigned short* __restrict__ t, int* __restrict__ flag)
{
    __shared__ int bad;
    if (threadIdx.x == 0) bad = 0;
    __syncthreads();
    int my = 0;
    for (int k = 0; k < 8; k++) {
        unsigned u = t[threadIdx.x + 256 * k];
        unsigned e = (u >> 7) & 0xFF;
        if (e >= 0xC0) my = 1;
    }
    if (my) atomicOr(&bad, 1);
    __syncthreads();
    if (threadIdx.x == 0) *flag = bad;
}

__global__ __launch_bounds__(256) void dbg_kernel(bf16* out, int n, float v)
{
    int i = blockIdx.x * 256 + threadIdx.x;
    if (i < n) out[i] = __float2bfloat16(v);
}

// ---------------------------------------------------------------------------
// MFMA GEMM: C[M,N](bf16 ws) = A[M,K] @ W[N,K]^T + bias[N], optional ReLU.
// Block = 256 thr = 4 waves; block tile 64(M)x64(N); wave -> 16(M)x64(N).
// ---------------------------------------------------------------------------
template <bool RELU>
__global__ __launch_bounds__(256) void mgemm_kernel(
    const void* __restrict__ A, int lda, size_t aOff, int aCode,
    const void* __restrict__ W, size_t wOff,
    const void* __restrict__ bias, size_t bOff,
    bf16* __restrict__ C, int ldc,
    int M, int N, int K, const int* __restrict__ flagp)
{
    const int fl = *flagp;
    const int am = decode(aCode, fl);
    const int tid = threadIdx.x;
    const int lane = tid & 63;
    const int wv = tid >> 6;
    const int l15 = lane & 15;
    const int quad = lane >> 4;
    const int bm = blockIdx.y * 64 + wv * 16;
    const int bn = blockIdx.x * 64;

    const int ar = min(bm + l15, M - 1);  // clamped A row (stores predicated)
    const size_t aBase = aOff + (size_t)ar * lda + quad * 8;

    f32x4 acc[4] = {};

    for (int k0 = 0; k0 < K; k0 += 32) {
        short8 af = loadFrag8(A, aBase + k0, am);
#pragma unroll
        for (int nt = 0; nt < 4; nt++) {
            int n = bn + nt * 16 + l15;
            short8 bfr = loadFrag8(W, wOff + (size_t)n * K + quad * 8 + k0, fl);
            acc[nt] = __builtin_amdgcn_mfma_f32_16x16x32_bf16(af, bfr, acc[nt], 0, 0, 0);
        }
    }

#pragma unroll
    for (int nt = 0; nt < 4; nt++) {
        int n = bn + nt * 16 + l15;
        float bv = ldF(bias, bOff + n, fl);
#pragma unroll
        for (int r = 0; r < 4; r++) {
            int row = bm + quad * 4 + r;
            if (row < M) {
                float v = acc[nt][r] + bv;
                if (RELU) v = fmaxf(v, 0.f);
                C[(size_t)row * ldc + n] = __float2bfloat16(v);
            }
        }
    }
}

// ---------------------------------------------------------------------------
__global__ __launch_bounds__(256) void add_kernel(
    const void* __restrict__ A, int aCode, const void* __restrict__ B,
    bf16* __restrict__ out, int n, const int* __restrict__ flagp)
{
    const int fl = *flagp;
    const int am = decode(aCode, fl);
    int i = blockIdx.x * 256 + threadIdx.x;
    if (i < n) out[i] = __float2bfloat16(ldF(A, i, am) + ldF(B, i, fl));
}

// ---------------------------------------------------------------------------
// Fused residual + LayerNorm over E=256 (unchanged).
// ---------------------------------------------------------------------------
__global__ __launch_bounds__(256) void ln_res_kernel(
    const bf16* __restrict__ A, const void* __restrict__ R, int rCode,
    const void* __restrict__ w, const void* __restrict__ b,
    void* __restrict__ out, int oCode, const int* __restrict__ flagp)
{
    const int fl = *flagp;
    const int rm = decode(rCode, fl);
    const int om = decode(oCode, fl);
    const int r = blockIdx.x, tid = threadIdx.x;
    const size_t o = (size_t)r * 256 + tid;
    float x = toF(A[o]) + ldF(R, o, rm);
    __shared__ float red[256];
    red[tid] = x;
    __syncthreads();
    for (int st = 128; st > 0; st >>= 1) {
        if (tid < st) red[tid] += red[tid + st];
        __syncthreads();
    }
    float mean = red[0] * (1.f / 256.f);
    __syncthreads();
    float dx = x - mean;
    red[tid] = dx * dx;
    __syncthreads();
    for (int st = 128; st > 0; st >>= 1) {
        if (tid < st) red[tid] += red[tid + st];
        __syncthreads();
    }
    float var = red[0] * (1.f / 256.f);
    float y = dx * rsqrtf(var + 1e-5f) * ldF(w, tid, fl) + ldF(b, tid, fl);
    stF(out, o, om, y);
}

// ---------------------------------------------------------------------------
// K transpose: K[(ki,b)][hd] (strided rows) -> KT[(b*256+hd)][ki] contiguous.
// Total = 2048*Lk elements, grid = total/256 exactly (Lk in {900,100}).
// Reads strided (few us total), writes coalesced.
// ---------------------------------------------------------------------------
__global__ __launch_bounds__(256) void transpose_k_kernel(
    const bf16* __restrict__ K, int ks0, int ks1,
    bf16* __restrict__ KT, int Lk)
{
    int i = blockIdx.x * 256 + threadIdx.x;  // i = c*Lk + ki, c = b*256 + hd
    int ki = i % Lk;
    int c = i / Lk;
    int b = c >> 8, hd = c & 255;
    KT[i] = K[(size_t)ki * ks0 + (size_t)b * ks1 + hd];
}

// ---------------------------------------------------------------------------
// Fused attention v2: K pre-transposed so QK loads are coalesced short4;
// PV vectorized 4-wide in d. One block per (qi, b, h).
// ---------------------------------------------------------------------------
__global__ __launch_bounds__(256) void attn_kernel(
    const bf16* __restrict__ Q, int qs0, int qs1,
    const bf16* __restrict__ KT,   // [(b*256 + h*32 + d)][Lk]
    const bf16* __restrict__ V, int vs0, int vs1,
    bf16* __restrict__ O, int Lk, float scale)
{
    const int blk = blockIdx.x;  // qi*64 + b*8 + h
    const int h = blk & 7;
    const int b = (blk >> 3) & 7;
    const int qi = blk >> 6;
    const int tid = threadIdx.x;

    __shared__ float qv[32];
    __shared__ float sc[928];
    __shared__ float red[256];
    __shared__ float oacc[32][32];  // [g][d]

    if (tid < 32) qv[tid] = toF(Q[(size_t)qi * qs0 + (size_t)b * qs1 + h * 32 + tid]);
    __syncthreads();

    // ---- QK^T: thread handles 4 consecutive ki via short4 loads (coalesced).
    // Lk is a multiple of 4 (900 / 100); addresses 8B-aligned.
    const int kv = tid * 4;
    float lmax = -1e30f;
    if (kv < Lk) {
        const bf16* Kb = KT + (size_t)(b * 256 + h * 32) * Lk + kv;
        float s0 = 0.f, s1 = 0.f, s2 = 0.f, s3 = 0.f;
#pragma unroll
        for (int d = 0; d < 32; d++) {
            short4 kk = *(const short4*)(Kb + (size_t)d * Lk);
            float qd = qv[d];
            s0 = fmaf(qd, b2f(kk.x), s0);
            s1 = fmaf(qd, b2f(kk.y), s1);
            s2 = fmaf(qd, b2f(kk.z), s2);
            s3 = fmaf(qd, b2f(kk.w), s3);
        }
        s0 *= scale; s1 *= scale; s2 *= scale; s3 *= scale;
        sc[kv + 0] = s0; sc[kv + 1] = s1; sc[kv + 2] = s2; sc[kv + 3] = s3;
        lmax = fmaxf(fmaxf(s0, s1), fmaxf(s2, s3));
    }
    red[tid] = lmax;
    __syncthreads();
    for (int st = 128; st > 0; st >>= 1) {
        if (tid < st) red[tid] = fmaxf(red[tid], red[tid + st]);
        __syncthreads();
    }
    float gmax = red[0];
    __syncthreads();
    float lsum = 0.f;
    for (int ki = tid; ki < Lk; ki += 256) {
        float e = expf(sc[ki] - gmax);
        sc[ki] = e;
        lsum += e;
    }
    red[tid] = lsum;
    __syncthreads();
    for (int st = 128; st > 0; st >>= 1) {
        if (tid < st) red[tid] += red[tid + st];
        __syncthreads();
    }
    float gsum = red[0];

    // ---- PV: thread owns 4 consecutive d (short4 V loads), 32 ki-groups.
    const int d4 = (tid & 7) * 4;
    const int g = tid >> 3;
    float p0 = 0.f, p1 = 0.f, p2 = 0.f, p3 = 0.f;
    const bf16* Vb = V + (size_t)b * vs1 + h * 32 + d4;
    for (int ki = g; ki < Lk; ki += 32) {
        float wgt = sc[ki];
        short4 vv = *(const short4*)(Vb + (size_t)ki * vs0);
        p0 = fmaf(wgt, b2f(vv.x), p0);
        p1 = fmaf(wgt, b2f(vv.y), p1);
        p2 = fmaf(wgt, b2f(vv.z), p2);
        p3 = fmaf(wgt, b2f(vv.w), p3);
    }
    oacc[g][d4 + 0] = p0;
    oacc[g][d4 + 1] = p1;
    oacc[g][d4 + 2] = p2;
    oacc[g][d4 + 3] = p3;
    __syncthreads();
    if (tid < 32) {
        float s = 0.f;
#pragma unroll
        for (int gg = 0; gg < 32; gg++) s += oacc[gg][tid];
        O[((size_t)qi * 8 + b) * 256 + h * 32 + tid] = __float2bfloat16(s / gsum);
    }
}

// ---------------------------------------------------------------------------
// Deformable sampling, single batch bb (unchanged).
// ---------------------------------------------------------------------------
__device__ __forceinline__ float sample_one(const bf16* __restrict__ val,
                                            int base, int HW, int yi, int xi,
                                            int hd32)
{
    bool valid = (xi >= 0) && (xi < HW) && (yi >= 0) && (yi < HW);
    int ix = min(max(xi, 0), HW - 1);
    int iy = min(max(yi, 0), HW - 1);
    size_t idx = (size_t)(base + iy * HW + ix) * 256 + hd32;
    float v = toF(val[idx]);
    return valid ? v : 0.f;
}

__global__ __launch_bounds__(256) void deform_kernel(
    const bf16* __restrict__ val,
    const bf16* __restrict__ off,
    const bf16* __restrict__ awl,
    const void* __restrict__ refp,
    bf16* __restrict__ samp, int bb, const int* __restrict__ flagp)
{
    const int fl = *flagp;
    const int levH[4] = {128, 64, 32, 16};
    const int levS[4] = {0, 16384, 20480, 21504};
    const int r = blockIdx.x * 8 + bb;
    const int tid = threadIdx.x;
    const int h = tid >> 5, d = tid & 31;
    const int hd32 = h * 32 + d;

    const bf16* lg = awl + (size_t)r * 128 + h * 16;
    float w[16];
    float mx = -1e30f;
#pragma unroll
    for (int i = 0; i < 16; i++) { w[i] = toF(lg[i]); mx = fmaxf(mx, w[i]); }
    float sm = 0.f;
#pragma unroll
    for (int i = 0; i < 16; i++) { w[i] = expf(w[i] - mx); sm += w[i]; }
    float inv = 1.f / sm;

    const bf16* offr = off + (size_t)r * 256 + h * 32;
    float acc = 0.f;
#pragma unroll
    for (int l = 0; l < 4; l++) {
        const int HW = levH[l];
        const int base = levS[l];
        float rx = ldF(refp, (size_t)r * 16 + l * 4 + 0, fl);
        float ry = ldF(refp, (size_t)r * 16 + l * 4 + 1, fl);
        float rw = ldF(refp, (size_t)r * 16 + l * 4 + 2, fl);
        float rh = ldF(refp, (size_t)r * 16 + l * 4 + 3, fl);
#pragma unroll
        for (int p = 0; p < 4; p++) {
            float ox = toF(offr[l * 8 + p * 2 + 0]);
            float oy = toF(offr[l * 8 + p * 2 + 1]);
            float locx = rx + ox * 0.125f * rw;   // off/NP * wh * 0.5
            float locy = ry + oy * 0.125f * rh;
            float x = locx * HW - 0.5f;
            float y = locy * HW - 0.5f;
            float x0f = floorf(x), y0f = floorf(y);
            int x0 = (int)x0f, y0 = (int)y0f;
            float fx = x - x0f, fy = y - y0f;
            float wgt = w[l * 4 + p] * inv;
            float s00 = sample_one(val, base, HW, y0,     x0,     hd32);
            float s01 = sample_one(val, base, HW, y0,     x0 + 1, hd32);
            float s10 = sample_one(val, base, HW, y0 + 1, x0,     hd32);
            float s11 = sample_one(val, base, HW, y0 + 1, x0 + 1, hd32);
            acc += wgt * (s00 * (1.f - fx) * (1.f - fy) + s01 * fx * (1.f - fy) +
                          s10 * (1.f - fx) * fy + s11 * fx * fy);
        }
    }
    samp[(size_t)r * 256 + tid] = __float2bfloat16(acc);
}

// ---------------------------------------------------------------------------
extern "C" void kernel_launch(void* const* d_in, const int* in_sizes, int n_in,
                              void* d_out, int out_size, void* d_ws, size_t ws_size,
                              hipStream_t stream)
{
    (void)in_sizes; (void)n_in;
    const void* tgt      = d_in[0];
    const void* tgt_pos  = d_in[1];
    const void* refp     = d_in[2];
    const void* mem_sup  = d_in[3];
    const void* memory   = d_in[4];
    const void* sa_in_w  = d_in[6];
    const void* sa_in_b  = d_in[7];
    const void* sa_out_w = d_in[8];
    const void* sa_out_b = d_in[9];
    const void* cs_in_w  = d_in[10];
    const void* cs_in_b  = d_in[11];
    const void* cs_out_w = d_in[12];
    const void* cs_out_b = d_in[13];
    const void* so_w = d_in[14];
    const void* so_b = d_in[15];
    const void* aw_w = d_in[16];
    const void* aw_b = d_in[17];
    const void* vp_w = d_in[18];
    const void* vp_b = d_in[19];
    const void* op_w = d_in[20];
    const void* op_b = d_in[21];
    const void* n1w = d_in[22];
    const void* n1b = d_in[23];
    const void* n2w = d_in[24];
    const void* n2b = d_in[25];
    const void* csnw = d_in[26];
    const void* csnb = d_in[27];
    const void* n3w = d_in[28];
    const void* n3b = d_in[29];
    const void* l1w = d_in[30];
    const void* l1b = d_in[31];
    const void* l2w = d_in[32];
    const void* l2b = d_in[33];

    const int S = 900 * 8 * 256;
    const size_t NEEDED = 29622528;
    const dim3 blk(256);

    if (ws_size < NEEDED) {
        dbg_kernel<<<(out_size + 255) / 256, blk, 0, stream>>>(
            (bf16*)d_out, out_size, (float)(ws_size >> 20));
        return;
    }

    char* base = (char*)d_ws;
    float* T5 = (float*)base;              // [S] f32
    bf16* B1  = (bf16*)(base + 7372800);   // [S]
    bf16* B2  = (bf16*)(base + 11059200);  // [2S]
    bf16* B3  = (bf16*)(base + 18432000);  // [S + 64K elems]
    bf16* B4  = (bf16*)(base + 22249472);  // [S]
    bf16* B5  = (bf16*)(base + 25935872);  // [S]
    int* FL   = (int*)(base + 29622272);

    const float scale = 0.1767766953f;  // 1/sqrt(32)
    const int MT = 7200;
    const int gy = 113;  // ceil(7200/64)

    detect_kernel<<<1, blk, 0, stream>>>((const unsigned short*)tgt, FL);

    // ---- self attention ----
    add_kernel<<<MT, blk, 0, stream>>>(tgt, 2, tgt_pos, B1, S, FL);
    mgemm_kernel<false><<<dim3(8, gy), blk, 0, stream>>>(
        B1, 256, 0, 0, sa_in_w, 0, sa_in_b, 0, B2, 512, MT, 512, 256, FL);  // q,k
    mgemm_kernel<false><<<dim3(4, gy), blk, 0, stream>>>(
        tgt, 256, 0, 2, sa_in_w, 131072, sa_in_b, 512, B3, 256, MT, 256, 256, FL);  // v
    // KT in B5 (dead until out-proj): 2048*900 elems, grid exact
    transpose_k_kernel<<<7200, blk, 0, stream>>>(B2 + 256, 4096, 512, B5, 900);
    attn_kernel<<<900 * 64, blk, 0, stream>>>(
        B2, 4096, 512, B5, B3, 2048, 256, B4, 900, scale);
    mgemm_kernel<false><<<dim3(4, gy), blk, 0, stream>>>(
        B4, 256, 0, 0, sa_out_w, 0, sa_out_b, 0, B5, 256, MT, 256, 256, FL);
    ln_res_kernel<<<MT, blk, 0, stream>>>(B5, tgt, 2, n2w, n2b, T5, 1, FL);

    // ---- cross attention (memory_support, Lk=100) ----
    add_kernel<<<MT, blk, 0, stream>>>(T5, 1, tgt_pos, B1, S, FL);
    mgemm_kernel<false><<<dim3(4, gy), blk, 0, stream>>>(
        B1, 256, 0, 0, cs_in_w, 0, cs_in_b, 0, B2, 256, MT, 256, 256, FL);  // q
    mgemm_kernel<false><<<dim3(8, 13), blk, 0, stream>>>(
        mem_sup, 256, 0, 2, cs_in_w, 65536, cs_in_b, 256, B3, 512, 800, 512, 256, FL);  // k,v
    transpose_k_kernel<<<800, blk, 0, stream>>>(B3, 512, 51200, B5, 100);
    attn_kernel<<<900 * 64, blk, 0, stream>>>(
        B2, 2048, 256, B5, B3 + 256, 512, 51200, B4, 100, scale);
    mgemm_kernel<false><<<dim3(4, gy), blk, 0, stream>>>(
        B4, 256, 0, 0, cs_out_w, 0, cs_out_b, 0, B5, 256, MT, 256, 256, FL);
    ln_res_kernel<<<MT, blk, 0, stream>>>(B5, T5, 1, csnw, csnb, T5, 1, FL);

    // ---- deformable attention ----
    add_kernel<<<MT, blk, 0, stream>>>(T5, 1, tgt_pos, B1, S, FL);  // query
    mgemm_kernel<false><<<dim3(4, gy), blk, 0, stream>>>(
        B1, 256, 0, 0, so_w, 0, so_b, 0, B4, 256, MT, 256, 256, FL);        // offsets
    mgemm_kernel<false><<<dim3(2, gy), blk, 0, stream>>>(
        B1, 256, 0, 0, aw_w, 0, aw_b, 0, B5, 128, MT, 128, 256, FL);        // aw logits
    for (int b = 0; b < 8; b++) {
        mgemm_kernel<false><<<dim3(4, 340), blk, 0, stream>>>(
            memory, 2048, (size_t)b * 256, 2, vp_w, 0, vp_b, 0, B2, 256,
            21760, 256, 256, FL);                                           // val proj
        deform_kernel<<<900, blk, 0, stream>>>(B2, B4, B5, refp, B1, b, FL);
    }
    mgemm_kernel<false><<<dim3(4, gy), blk, 0, stream>>>(
        B1, 256, 0, 0, op_w, 0, op_b, 0, B5, 256, MT, 256, 256, FL);        // out proj
    ln_res_kernel<<<MT, blk, 0, stream>>>(B5, T5, 1, n1w, n1b, T5, 1, FL);

    // ---- FFN (5 chunks of 1440 rows; hidden chunk in B2) ----
    for (int c = 0; c < 5; c++) {
        int m0 = c * 1440;
        mgemm_kernel<true><<<dim3(16, 23), blk, 0, stream>>>(
            T5, 256, (size_t)m0 * 256, 1, l1w, 0, l1b, 0, B2, 1024,
            1440, 1024, 256, FL);
        mgemm_kernel<false><<<dim3(4, 23), blk, 0, stream>>>(
            B2, 1024, 0, 0, l2w, 0, l2b, 0, B5 + (size_t)m0 * 256, 256,
            1440, 256, 1024, FL);
    }
    ln_res_kernel<<<MT, blk, 0, stream>>>(B5, T5, 1, n3w, n3b, d_out, 2, FL);
}

// Round 3
// 1552.441 us; speedup vs baseline: 1.6853x; 1.3155x over previous
//
#include <hip/hip_runtime.h>
#include <hip/hip_bf16.h>

// DeformableTransformerDecoderLayer on MI355X — Round 6.
// R5: 2042 us. Self-attn 460 us, MfmaUtil=0, VALU 59%, VGPR=36 -> scalar QK
// loop is L2-latency-bound (1800B-stride short4 loads, ~6 in flight). This
// round: MFMA flash attention (one block per (b,h) x 64-row Q-tile; K-tiles
// of 64; mfma_f32_16x16x32_bf16 for QK^T and PV; P via padded LDS tile).
// V is pre-transposed to [(b,h,d)][LkPad] with zeroed pad (self: T5 region,
// dead until ln_res; cross: B1, dead after q GEMM). Scalar attn + K
// transpose removed. Everything else unchanged.
//   E=256 NH=8 HD=32 NL=4 NP=4 DFFN=1024, nq=900 bs=8 Ls=100 Lv=21760.
//
// Arena (byte offsets), S = 7200*256 = 1,843,200 elems:
//   T5 f32 [S]        @ 0           running tgt | self VT (pre-LN scratch)
//   B1 bf16 [S]       @ 7,372,800   q=tgt(+pos) | cross VT | deform samp
//   B2 bf16 [2S]      @ 11,059,200  self QK | cross q | val(spans B3) | FFN hidden
//   B3 bf16 [S+64K]   @ 18,432,000  self V | cross KV | val tail
//   B4 bf16 [S]       @ 22,249,472  attn out | deform off
//   B5 bf16 [S]       @ 25,935,872  proj out | deform awl
//   FLAG int          @ 29,622,272  detected input dtype (1=f32, 0=bf16)
// NEEDED = 29,622,528 bytes.

typedef __hip_bfloat16 bf16;
typedef __attribute__((ext_vector_type(8))) short short8;
typedef __attribute__((ext_vector_type(4))) float f32x4;

__device__ __forceinline__ float toF(bf16 x) { return __bfloat162float(x); }

__device__ __forceinline__ float ldF(const void* p, size_t i, int f32mode) {
    if (f32mode) return ((const float*)p)[i];
    return __bfloat162float(((const bf16*)p)[i]);
}
__device__ __forceinline__ void stF(void* p, size_t i, int f32mode, float v) {
    if (f32mode) ((float*)p)[i] = v;
    else ((bf16*)p)[i] = __float2bfloat16(v);
}
// mode codes: 0 = bf16 (ws), 1 = f32 (ws), 2 = external (use flag)
__device__ __forceinline__ int decode(int code, int fl) { return code == 2 ? fl : code; }

__device__ __forceinline__ short f2b(float x) {
    bf16 h = __float2bfloat16(x);
    return *(short*)&h;
}

// Load 8 consecutive elements starting at element idx as a bf16x8 fragment.
__device__ __forceinline__ short8 loadFrag8(const void* p, size_t idx, int f32m) {
    short8 r;
    if (f32m) {
        const float4* q = (const float4*)((const float*)p + idx);
        float4 u = q[0];
        float4 v = q[1];
        r[0] = f2b(u.x); r[1] = f2b(u.y); r[2] = f2b(u.z); r[3] = f2b(u.w);
        r[4] = f2b(v.x); r[5] = f2b(v.y); r[6] = f2b(v.z); r[7] = f2b(v.w);
    } else {
        r = *(const short8*)((const bf16*)p + idx);
    }
    return r;
}

// ---------------------------------------------------------------------------
// Input dtype detector (unchanged).
// ---------------------------------------------------------------------------
__global__ __launch_bounds__(256) void detect_kernel(
    const unsigned short* __restrict__ t, int* __restrict__ flag)
{
    __shared__ int bad;
    if (threadIdx.x == 0) bad = 0;
    __syncthreads();
    int my = 0;
    for (int k = 0; k < 8; k++) {
        unsigned u = t[threadIdx.x + 256 * k];
        unsigned e = (u >> 7) & 0xFF;
        if (e >= 0xC0) my = 1;
    }
    if (my) atomicOr(&bad, 1);
    __syncthreads();
    if (threadIdx.x == 0) *flag = bad;
}

__global__ __launch_bounds__(256) void dbg_kernel(bf16* out, int n, float v)
{
    int i = blockIdx.x * 256 + threadIdx.x;
    if (i < n) out[i] = __float2bfloat16(v);
}

// ---------------------------------------------------------------------------
// MFMA GEMM: C[M,N](bf16 ws) = A[M,K] @ W[N,K]^T + bias[N], optional ReLU.
// (unchanged)
// ---------------------------------------------------------------------------
template <bool RELU>
__global__ __launch_bounds__(256) void mgemm_kernel(
    const void* __restrict__ A, int lda, size_t aOff, int aCode,
    const void* __restrict__ W, size_t wOff,
    const void* __restrict__ bias, size_t bOff,
    bf16* __restrict__ C, int ldc,
    int M, int N, int K, const int* __restrict__ flagp)
{
    const int fl = *flagp;
    const int am = decode(aCode, fl);
    const int tid = threadIdx.x;
    const int lane = tid & 63;
    const int wv = tid >> 6;
    const int l15 = lane & 15;
    const int quad = lane >> 4;
    const int bm = blockIdx.y * 64 + wv * 16;
    const int bn = blockIdx.x * 64;

    const int ar = min(bm + l15, M - 1);  // clamped A row (stores predicated)
    const size_t aBase = aOff + (size_t)ar * lda + quad * 8;

    f32x4 acc[4] = {};

    for (int k0 = 0; k0 < K; k0 += 32) {
        short8 af = loadFrag8(A, aBase + k0, am);
#pragma unroll
        for (int nt = 0; nt < 4; nt++) {
            int n = bn + nt * 16 + l15;
            short8 bfr = loadFrag8(W, wOff + (size_t)n * K + quad * 8 + k0, fl);
            acc[nt] = __builtin_amdgcn_mfma_f32_16x16x32_bf16(af, bfr, acc[nt], 0, 0, 0);
        }
    }

#pragma unroll
    for (int nt = 0; nt < 4; nt++) {
        int n = bn + nt * 16 + l15;
        float bv = ldF(bias, bOff + n, fl);
#pragma unroll
        for (int r = 0; r < 4; r++) {
            int row = bm + quad * 4 + r;
            if (row < M) {
                float v = acc[nt][r] + bv;
                if (RELU) v = fmaxf(v, 0.f);
                C[(size_t)row * ldc + n] = __float2bfloat16(v);
            }
        }
    }
}

// ---------------------------------------------------------------------------
__global__ __launch_bounds__(256) void add_kernel(
    const void* __restrict__ A, int aCode, const void* __restrict__ B,
    bf16* __restrict__ out, int n, const int* __restrict__ flagp)
{
    const int fl = *flagp;
    const int am = decode(aCode, fl);
    int i = blockIdx.x * 256 + threadIdx.x;
    if (i < n) out[i] = __float2bfloat16(ldF(A, i, am) + ldF(B, i, fl));
}

// ---------------------------------------------------------------------------
// Fused residual + LayerNorm over E=256 (unchanged).
// ---------------------------------------------------------------------------
__global__ __launch_bounds__(256) void ln_res_kernel(
    const bf16* __restrict__ A, const void* __restrict__ R, int rCode,
    const void* __restrict__ w, const void* __restrict__ b,
    void* __restrict__ out, int oCode, const int* __restrict__ flagp)
{
    const int fl = *flagp;
    const int rm = decode(rCode, fl);
    const int om = decode(oCode, fl);
    const int r = blockIdx.x, tid = threadIdx.x;
    const size_t o = (size_t)r * 256 + tid;
    float x = toF(A[o]) + ldF(R, o, rm);
    __shared__ float red[256];
    red[tid] = x;
    __syncthreads();
    for (int st = 128; st > 0; st >>= 1) {
        if (tid < st) red[tid] += red[tid + st];
        __syncthreads();
    }
    float mean = red[0] * (1.f / 256.f);
    __syncthreads();
    float dx = x - mean;
    red[tid] = dx * dx;
    __syncthreads();
    for (int st = 128; st > 0; st >>= 1) {
        if (tid < st) red[tid] += red[tid + st];
        __syncthreads();
    }
    float var = red[0] * (1.f / 256.f);
    float y = dx * rsqrtf(var + 1e-5f) * ldF(w, tid, fl) + ldF(b, tid, fl);
    stF(out, o, om, y);
}

// ---------------------------------------------------------------------------
// V transpose with zero pad: V[(ki,b)][hd] -> VT[(b*256+hd)][lkp], cols
// [Lk, lkp) zeroed. Total = 2048*lkp elems, grid = total/256 exactly.
// ---------------------------------------------------------------------------
__global__ __launch_bounds__(256) void transpose_v_kernel(
    const bf16* __restrict__ V, int vs0, int vs1,
    bf16* __restrict__ VT, int Lk, int lkp)
{
    int i = blockIdx.x * 256 + threadIdx.x;  // i = ch*lkp + kp
    int kp = i % lkp;
    int ch = i / lkp;
    int b = ch >> 8, hd = ch & 255;
    bf16 v = __float2bfloat16(0.f);
    if (kp < Lk) v = V[(size_t)kp * vs0 + (size_t)b * vs1 + hd];
    VT[i] = v;
}

// ---------------------------------------------------------------------------
// MFMA flash attention. Grid (64 = b*8+h, nqt); block 256 = 4 waves; wave w
// owns q-rows [qt*64 + w*16, +16). K-tiles of 64; D=32 (one MFMA per S tile).
// Q rows at q*qs0 + b*qs1 + h*32; K rows at k*ks0 + b*ks1 + h*32 (bf16).
// VT: [(b*256+h*32+d)][lkp], pad cols zeroed. O: [(q*8+b)*256 + h*32 + d].
// Fragment geometry identical to mgemm_kernel (harness-verified):
//   A/B frag = [row][k=quad*8+j]; C/D: col=lane&15, row=quad*4+reg.
// P goes through LDS (row stride 72 elems = 144B: 16B-aligned b128 reads,
// 2-way banks = free) to convert C-layout -> A-layout for the PV MFMA.
// ---------------------------------------------------------------------------
__global__ __launch_bounds__(256) void fattn_kernel(
    const bf16* __restrict__ Q, int qs0, int qs1,
    const bf16* __restrict__ K, int ks0, int ks1,
    const bf16* __restrict__ VT, int lkp,
    bf16* __restrict__ O, int Lk, float scale)
{
    const int bh = blockIdx.x;
    const int b = bh >> 3, h = bh & 7;
    const int qt = blockIdx.y;
    const int tid = threadIdx.x;
    const int w = tid >> 6;
    const int lane = tid & 63;
    const int l15 = lane & 15;
    const int quad = lane >> 4;

    __shared__ short Pl[4][16][72];

    // Persistent Q fragment: row q0+l15 (clamped), k = quad*8..+7 (D=32).
    const int q0 = qt * 64 + w * 16;
    const int qr = min(q0 + l15, 899);
    short8 aq = *(const short8*)(Q + (size_t)qr * qs0 + (size_t)b * qs1 + h * 32 + quad * 8);

    f32x4 accO0 = {}, accO1 = {};
    float mrow[4] = {-1e30f, -1e30f, -1e30f, -1e30f};
    float lrow[4] = {0.f, 0.f, 0.f, 0.f};

    const bf16* Kb = K + (size_t)b * ks1 + h * 32 + quad * 8;
    const bf16* VTb = VT + (size_t)(b * 256 + h * 32) * lkp;

    const int nkt = (Lk + 63) >> 6;
    for (int kt = 0; kt < nkt; kt++) {
        const int k0 = kt * 64;
        // ---- S tile: s[nt] holds S[q0+quad*4+r][k0+nt*16+l15] ----
        float sv[4][4];
#pragma unroll
        for (int nt = 0; nt < 4; nt++) {
            int kk = k0 + nt * 16 + l15;
            int krow = min(kk, Lk - 1);
            short8 bk = *(const short8*)(Kb + (size_t)krow * ks0);
            f32x4 z = {};
            f32x4 s = __builtin_amdgcn_mfma_f32_16x16x32_bf16(aq, bk, z, 0, 0, 0);
            bool ok = kk < Lk;
#pragma unroll
            for (int r = 0; r < 4; r++) sv[nt][r] = ok ? s[r] * scale : -1e30f;
        }
        // ---- online softmax (per q-row = per (quad, r), uniform over l15) ----
        float mnew[4], fr[4];
#pragma unroll
        for (int r = 0; r < 4; r++) {
            float t = fmaxf(fmaxf(sv[0][r], sv[1][r]), fmaxf(sv[2][r], sv[3][r]));
            t = fmaxf(t, __shfl_xor(t, 1));
            t = fmaxf(t, __shfl_xor(t, 2));
            t = fmaxf(t, __shfl_xor(t, 4));
            t = fmaxf(t, __shfl_xor(t, 8));
            mnew[r] = fmaxf(mrow[r], t);
            fr[r] = __expf(mrow[r] - mnew[r]);
            mrow[r] = mnew[r];
        }
#pragma unroll
        for (int r = 0; r < 4; r++) {
            float p0 = __expf(sv[0][r] - mnew[r]);
            float p1 = __expf(sv[1][r] - mnew[r]);
            float p2 = __expf(sv[2][r] - mnew[r]);
            float p3 = __expf(sv[3][r] - mnew[r]);
            int row = quad * 4 + r;
            Pl[w][row][l15]      = f2b(p0);
            Pl[w][row][16 + l15] = f2b(p1);
            Pl[w][row][32 + l15] = f2b(p2);
            Pl[w][row][48 + l15] = f2b(p3);
            float t = p0 + p1 + p2 + p3;
            t += __shfl_xor(t, 1);
            t += __shfl_xor(t, 2);
            t += __shfl_xor(t, 4);
            t += __shfl_xor(t, 8);
            lrow[r] = lrow[r] * fr[r] + t;
            accO0[r] *= fr[r];
            accO1[r] *= fr[r];
        }
        // ---- PV: O += P @ V (A = P rows from LDS, B = VT rows) ----
#pragma unroll
        for (int kt2 = 0; kt2 < 2; kt2++) {
            short8 pa = *(const short8*)&Pl[w][l15][kt2 * 32 + quad * 8];
            short8 v0 = *(const short8*)(VTb + (size_t)l15 * lkp + k0 + kt2 * 32 + quad * 8);
            short8 v1 = *(const short8*)(VTb + (size_t)(16 + l15) * lkp + k0 + kt2 * 32 + quad * 8);
            accO0 = __builtin_amdgcn_mfma_f32_16x16x32_bf16(pa, v0, accO0, 0, 0, 0);
            accO1 = __builtin_amdgcn_mfma_f32_16x16x32_bf16(pa, v1, accO1, 0, 0, 0);
        }
    }
    // ---- epilogue: O[q][d] / l, predicated on q < 900 ----
#pragma unroll
    for (int r = 0; r < 4; r++) {
        int q = q0 + quad * 4 + r;
        if (q < 900) {
            float inv = 1.f / lrow[r];
            size_t o = ((size_t)q * 8 + b) * 256 + h * 32;
            O[o + l15]      = __float2bfloat16(accO0[r] * inv);
            O[o + 16 + l15] = __float2bfloat16(accO1[r] * inv);
        }
    }
}

// ---------------------------------------------------------------------------
// Deformable sampling, single batch bb (unchanged).
// ---------------------------------------------------------------------------
__device__ __forceinline__ float sample_one(const bf16* __restrict__ val,
                                            int base, int HW, int yi, int xi,
                                            int hd32)
{
    bool valid = (xi >= 0) && (xi < HW) && (yi >= 0) && (yi < HW);
    int ix = min(max(xi, 0), HW - 1);
    int iy = min(max(yi, 0), HW - 1);
    size_t idx = (size_t)(base + iy * HW + ix) * 256 + hd32;
    float v = toF(val[idx]);
    return valid ? v : 0.f;
}

__global__ __launch_bounds__(256) void deform_kernel(
    const bf16* __restrict__ val,
    const bf16* __restrict__ off,
    const bf16* __restrict__ awl,
    const void* __restrict__ refp,
    bf16* __restrict__ samp, int bb, const int* __restrict__ flagp)
{
    const int fl = *flagp;
    const int levH[4] = {128, 64, 32, 16};
    const int levS[4] = {0, 16384, 20480, 21504};
    const int r = blockIdx.x * 8 + bb;
    const int tid = threadIdx.x;
    const int h = tid >> 5, d = tid & 31;
    const int hd32 = h * 32 + d;

    const bf16* lg = awl + (size_t)r * 128 + h * 16;
    float w[16];
    float mx = -1e30f;
#pragma unroll
    for (int i = 0; i < 16; i++) { w[i] = toF(lg[i]); mx = fmaxf(mx, w[i]); }
    float sm = 0.f;
#pragma unroll
    for (int i = 0; i < 16; i++) { w[i] = expf(w[i] - mx); sm += w[i]; }
    float inv = 1.f / sm;

    const bf16* offr = off + (size_t)r * 256 + h * 32;
    float acc = 0.f;
#pragma unroll
    for (int l = 0; l < 4; l++) {
        const int HW = levH[l];
        const int base = levS[l];
        float rx = ldF(refp, (size_t)r * 16 + l * 4 + 0, fl);
        float ry = ldF(refp, (size_t)r * 16 + l * 4 + 1, fl);
        float rw = ldF(refp, (size_t)r * 16 + l * 4 + 2, fl);
        float rh = ldF(refp, (size_t)r * 16 + l * 4 + 3, fl);
#pragma unroll
        for (int p = 0; p < 4; p++) {
            float ox = toF(offr[l * 8 + p * 2 + 0]);
            float oy = toF(offr[l * 8 + p * 2 + 1]);
            float locx = rx + ox * 0.125f * rw;   // off/NP * wh * 0.5
            float locy = ry + oy * 0.125f * rh;
            float x = locx * HW - 0.5f;
            float y = locy * HW - 0.5f;
            float x0f = floorf(x), y0f = floorf(y);
            int x0 = (int)x0f, y0 = (int)y0f;
            float fx = x - x0f, fy = y - y0f;
            float wgt = w[l * 4 + p] * inv;
            float s00 = sample_one(val, base, HW, y0,     x0,     hd32);
            float s01 = sample_one(val, base, HW, y0,     x0 + 1, hd32);
            float s10 = sample_one(val, base, HW, y0 + 1, x0,     hd32);
            float s11 = sample_one(val, base, HW, y0 + 1, x0 + 1, hd32);
            acc += wgt * (s00 * (1.f - fx) * (1.f - fy) + s01 * fx * (1.f - fy) +
                          s10 * (1.f - fx) * fy + s11 * fx * fy);
        }
    }
    samp[(size_t)r * 256 + tid] = __float2bfloat16(acc);
}

// ---------------------------------------------------------------------------
extern "C" void kernel_launch(void* const* d_in, const int* in_sizes, int n_in,
                              void* d_out, int out_size, void* d_ws, size_t ws_size,
                              hipStream_t stream)
{
    (void)in_sizes; (void)n_in;
    const void* tgt      = d_in[0];
    const void* tgt_pos  = d_in[1];
    const void* refp     = d_in[2];
    const void* mem_sup  = d_in[3];
    const void* memory   = d_in[4];
    const void* sa_in_w  = d_in[6];
    const void* sa_in_b  = d_in[7];
    const void* sa_out_w = d_in[8];
    const void* sa_out_b = d_in[9];
    const void* cs_in_w  = d_in[10];
    const void* cs_in_b  = d_in[11];
    const void* cs_out_w = d_in[12];
    const void* cs_out_b = d_in[13];
    const void* so_w = d_in[14];
    const void* so_b = d_in[15];
    const void* aw_w = d_in[16];
    const void* aw_b = d_in[17];
    const void* vp_w = d_in[18];
    const void* vp_b = d_in[19];
    const void* op_w = d_in[20];
    const void* op_b = d_in[21];
    const void* n1w = d_in[22];
    const void* n1b = d_in[23];
    const void* n2w = d_in[24];
    const void* n2b = d_in[25];
    const void* csnw = d_in[26];
    const void* csnb = d_in[27];
    const void* n3w = d_in[28];
    const void* n3b = d_in[29];
    const void* l1w = d_in[30];
    const void* l1b = d_in[31];
    const void* l2w = d_in[32];
    const void* l2b = d_in[33];

    const int S = 900 * 8 * 256;
    const size_t NEEDED = 29622528;
    const dim3 blk(256);

    if (ws_size < NEEDED) {
        dbg_kernel<<<(out_size + 255) / 256, blk, 0, stream>>>(
            (bf16*)d_out, out_size, (float)(ws_size >> 20));
        return;
    }

    char* base = (char*)d_ws;
    float* T5 = (float*)base;              // [S] f32
    bf16* B1  = (bf16*)(base + 7372800);   // [S]
    bf16* B2  = (bf16*)(base + 11059200);  // [2S]
    bf16* B3  = (bf16*)(base + 18432000);  // [S + 64K elems]
    bf16* B4  = (bf16*)(base + 22249472);  // [S]
    bf16* B5  = (bf16*)(base + 25935872);  // [S]
    int* FL   = (int*)(base + 29622272);

    const float scale = 0.1767766953f;  // 1/sqrt(32)
    const int MT = 7200;
    const int gy = 113;  // ceil(7200/64)

    detect_kernel<<<1, blk, 0, stream>>>((const unsigned short*)tgt, FL);

    // ---- self attention (Lk=900, LkPad=960; VT in T5 region, dead pre-LN) ----
    add_kernel<<<MT, blk, 0, stream>>>(tgt, 2, tgt_pos, B1, S, FL);
    mgemm_kernel<false><<<dim3(8, gy), blk, 0, stream>>>(
        B1, 256, 0, 0, sa_in_w, 0, sa_in_b, 0, B2, 512, MT, 512, 256, FL);  // q,k
    mgemm_kernel<false><<<dim3(4, gy), blk, 0, stream>>>(
        tgt, 256, 0, 2, sa_in_w, 131072, sa_in_b, 512, B3, 256, MT, 256, 256, FL);  // v
    transpose_v_kernel<<<7680, blk, 0, stream>>>(B3, 2048, 256, (bf16*)T5, 900, 960);
    fattn_kernel<<<dim3(64, 15), blk, 0, stream>>>(
        B2, 4096, 512, B2 + 256, 4096, 512, (bf16*)T5, 960, B4, 900, scale);
    mgemm_kernel<false><<<dim3(4, gy), blk, 0, stream>>>(
        B4, 256, 0, 0, sa_out_w, 0, sa_out_b, 0, B5, 256, MT, 256, 256, FL);
    ln_res_kernel<<<MT, blk, 0, stream>>>(B5, tgt, 2, n2w, n2b, T5, 1, FL);

    // ---- cross attention (memory_support, Lk=100, LkPad=128; VT in B1) ----
    add_kernel<<<MT, blk, 0, stream>>>(T5, 1, tgt_pos, B1, S, FL);
    mgemm_kernel<false><<<dim3(4, gy), blk, 0, stream>>>(
        B1, 256, 0, 0, cs_in_w, 0, cs_in_b, 0, B2, 256, MT, 256, 256, FL);  // q
    mgemm_kernel<false><<<dim3(8, 13), blk, 0, stream>>>(
        mem_sup, 256, 0, 2, cs_in_w, 65536, cs_in_b, 256, B3, 512, 800, 512, 256, FL);  // k,v
    transpose_v_kernel<<<1024, blk, 0, stream>>>(B3 + 256, 512, 51200, B1, 100, 128);
    fattn_kernel<<<dim3(64, 15), blk, 0, stream>>>(
        B2, 2048, 256, B3, 512, 51200, B1, 128, B4, 100, scale);
    mgemm_kernel<false><<<dim3(4, gy), blk, 0, stream>>>(
        B4, 256, 0, 0, cs_out_w, 0, cs_out_b, 0, B5, 256, MT, 256, 256, FL);
    ln_res_kernel<<<MT, blk, 0, stream>>>(B5, T5, 1, csnw, csnb, T5, 1, FL);

    // ---- deformable attention ----
    add_kernel<<<MT, blk, 0, stream>>>(T5, 1, tgt_pos, B1, S, FL);  // query
    mgemm_kernel<false><<<dim3(4, gy), blk, 0, stream>>>(
        B1, 256, 0, 0, so_w, 0, so_b, 0, B4, 256, MT, 256, 256, FL);        // offsets
    mgemm_kernel<false><<<dim3(2, gy), blk, 0, stream>>>(
        B1, 256, 0, 0, aw_w, 0, aw_b, 0, B5, 128, MT, 128, 256, FL);        // aw logits
    for (int b = 0; b < 8; b++) {
        mgemm_kernel<false><<<dim3(4, 340), blk, 0, stream>>>(
            memory, 2048, (size_t)b * 256, 2, vp_w, 0, vp_b, 0, B2, 256,
            21760, 256, 256, FL);                                           // val proj
        deform_kernel<<<900, blk, 0, stream>>>(B2, B4, B5, refp, B1, b, FL);
    }
    mgemm_kernel<false><<<dim3(4, gy), blk, 0, stream>>>(
        B1, 256, 0, 0, op_w, 0, op_b, 0, B5, 256, MT, 256, 256, FL);        // out proj
    ln_res_kernel<<<MT, blk, 0, stream>>>(B5, T5, 1, n1w, n1b, T5, 1, FL);

    // ---- FFN (5 chunks of 1440 rows; hidden chunk in B2) ----
    for (int c = 0; c < 5; c++) {
        int m0 = c * 1440;
        mgemm_kernel<true><<<dim3(16, 23), blk, 0, stream>>>(
            T5, 256, (size_t)m0 * 256, 1, l1w, 0, l1b, 0, B2, 1024,
            1440, 1024, 256, FL);
        mgemm_kernel<false><<<dim3(4, 23), blk, 0, stream>>>(
            B2, 1024, 0, 0, l2w, 0, l2b, 0, B5 + (size_t)m0 * 256, 256,
            1440, 256, 1024, FL);
    }
    ln_res_kernel<<<MT, blk, 0, stream>>>(B5, T5, 1, n3w, n3b, d_out, 2, FL);
}

// Round 4
// 1274.906 us; speedup vs baseline: 2.0521x; 1.2177x over previous
//
#include <hip/hip_runtime.h>
#include <hip/hip_bf16.h>

// DeformableTransformerDecoderLayer on MI355X — Round 7.
// R6: 1552 us; top-5 now all harness fills (713 MB poison -> ws ~713 MB).
// Remaining time attributed by arithmetic to the 8x (val-proj + deform)
// serial loop (deform: 900 blocks = 3.5 waves/SIMD, latency-bound gathers).
// This round: VAL[8][21760][256] (89 MB) in the unused workspace; ONE
// val-proj GEMM dispatch (blockIdx.z = batch) + ONE deform dispatch of
// 7200 blocks; FFN collapsed to single l1+l2 via H[7200][1024] (14.7 MB).
//   E=256 NH=8 HD=32 NL=4 NP=4 DFFN=1024, nq=900 bs=8 Ls=100 Lv=21760.
//
// Arena (byte offsets), S = 7200*256 = 1,843,200 elems:
//   T5 f32 [S]        @ 0            running tgt | self VT (pre-LN scratch)
//   B1 bf16 [S]       @ 7,372,800    q=tgt(+pos) | cross VT | deform samp
//   B2 bf16 [2S]      @ 11,059,200   self QK | cross q | (unused mid)
//   B3 bf16 [S+64K]   @ 18,432,000   self V | cross KV
//   B4 bf16 [S]       @ 22,249,472   attn out | deform off
//   B5 bf16 [S]       @ 25,935,872   proj out | deform awl
//   VAL bf16 [8*21760*256] @ 29,622,272   all-batch projected value
//   H  bf16 [7200*1024]    @ 118,751,232  FFN hidden
//   FLAG int          @ 133,496,832  detected input dtype (1=f32, 0=bf16)
// NEEDED = 133,496,836 bytes (ws observed ~713 MB via poison fill size).

typedef __hip_bfloat16 bf16;
typedef __attribute__((ext_vector_type(8))) short short8;
typedef __attribute__((ext_vector_type(4))) float f32x4;

__device__ __forceinline__ float toF(bf16 x) { return __bfloat162float(x); }

__device__ __forceinline__ float ldF(const void* p, size_t i, int f32mode) {
    if (f32mode) return ((const float*)p)[i];
    return __bfloat162float(((const bf16*)p)[i]);
}
__device__ __forceinline__ void stF(void* p, size_t i, int f32mode, float v) {
    if (f32mode) ((float*)p)[i] = v;
    else ((bf16*)p)[i] = __float2bfloat16(v);
}
// mode codes: 0 = bf16 (ws), 1 = f32 (ws), 2 = external (use flag)
__device__ __forceinline__ int decode(int code, int fl) { return code == 2 ? fl : code; }

__device__ __forceinline__ short f2b(float x) {
    bf16 h = __float2bfloat16(x);
    return *(short*)&h;
}

// Load 8 consecutive elements starting at element idx as a bf16x8 fragment.
__device__ __forceinline__ short8 loadFrag8(const void* p, size_t idx, int f32m) {
    short8 r;
    if (f32m) {
        const float4* q = (const float4*)((const float*)p + idx);
        float4 u = q[0];
        float4 v = q[1];
        r[0] = f2b(u.x); r[1] = f2b(u.y); r[2] = f2b(u.z); r[3] = f2b(u.w);
        r[4] = f2b(v.x); r[5] = f2b(v.y); r[6] = f2b(v.z); r[7] = f2b(v.w);
    } else {
        r = *(const short8*)((const bf16*)p + idx);
    }
    return r;
}

// ---------------------------------------------------------------------------
// Input dtype detector (unchanged).
// ---------------------------------------------------------------------------
__global__ __launch_bounds__(256) void detect_kernel(
    const unsigned short* __restrict__ t, int* __restrict__ flag)
{
    __shared__ int bad;
    if (threadIdx.x == 0) bad = 0;
    __syncthreads();
    int my = 0;
    for (int k = 0; k < 8; k++) {
        unsigned u = t[threadIdx.x + 256 * k];
        unsigned e = (u >> 7) & 0xFF;
        if (e >= 0xC0) my = 1;
    }
    if (my) atomicOr(&bad, 1);
    __syncthreads();
    if (threadIdx.x == 0) *flag = bad;
}

__global__ __launch_bounds__(256) void dbg_kernel(bf16* out, int n, float v)
{
    int i = blockIdx.x * 256 + threadIdx.x;
    if (i < n) out[i] = __float2bfloat16(v);
}

// ---------------------------------------------------------------------------
// MFMA GEMM: C[M,N](bf16 ws) = A[M,K] @ W[N,K]^T + bias[N], optional ReLU.
// blockIdx.z batching: A element offset += z*aZ, C element offset += z*cZ.
// ---------------------------------------------------------------------------
template <bool RELU>
__global__ __launch_bounds__(256) void mgemm_kernel(
    const void* __restrict__ A, int lda, size_t aOff, int aCode,
    const void* __restrict__ W, size_t wOff,
    const void* __restrict__ bias, size_t bOff,
    bf16* __restrict__ C, int ldc,
    int M, int N, int K, size_t aZ, size_t cZ, const int* __restrict__ flagp)
{
    const int fl = *flagp;
    const int am = decode(aCode, fl);
    const int tid = threadIdx.x;
    const int lane = tid & 63;
    const int wv = tid >> 6;
    const int l15 = lane & 15;
    const int quad = lane >> 4;
    const int bm = blockIdx.y * 64 + wv * 16;
    const int bn = blockIdx.x * 64;
    const size_t zA = (size_t)blockIdx.z * aZ;
    const size_t zC = (size_t)blockIdx.z * cZ;

    const int ar = min(bm + l15, M - 1);  // clamped A row (stores predicated)
    const size_t aBase = aOff + zA + (size_t)ar * lda + quad * 8;

    f32x4 acc[4] = {};

    for (int k0 = 0; k0 < K; k0 += 32) {
        short8 af = loadFrag8(A, aBase + k0, am);
#pragma unroll
        for (int nt = 0; nt < 4; nt++) {
            int n = bn + nt * 16 + l15;
            short8 bfr = loadFrag8(W, wOff + (size_t)n * K + quad * 8 + k0, fl);
            acc[nt] = __builtin_amdgcn_mfma_f32_16x16x32_bf16(af, bfr, acc[nt], 0, 0, 0);
        }
    }

#pragma unroll
    for (int nt = 0; nt < 4; nt++) {
        int n = bn + nt * 16 + l15;
        float bv = ldF(bias, bOff + n, fl);
#pragma unroll
        for (int r = 0; r < 4; r++) {
            int row = bm + quad * 4 + r;
            if (row < M) {
                float v = acc[nt][r] + bv;
                if (RELU) v = fmaxf(v, 0.f);
                C[zC + (size_t)row * ldc + n] = __float2bfloat16(v);
            }
        }
    }
}

// ---------------------------------------------------------------------------
__global__ __launch_bounds__(256) void add_kernel(
    const void* __restrict__ A, int aCode, const void* __restrict__ B,
    bf16* __restrict__ out, int n, const int* __restrict__ flagp)
{
    const int fl = *flagp;
    const int am = decode(aCode, fl);
    int i = blockIdx.x * 256 + threadIdx.x;
    if (i < n) out[i] = __float2bfloat16(ldF(A, i, am) + ldF(B, i, fl));
}

// ---------------------------------------------------------------------------
// Fused residual + LayerNorm over E=256 (unchanged).
// ---------------------------------------------------------------------------
__global__ __launch_bounds__(256) void ln_res_kernel(
    const bf16* __restrict__ A, const void* __restrict__ R, int rCode,
    const void* __restrict__ w, const void* __restrict__ b,
    void* __restrict__ out, int oCode, const int* __restrict__ flagp)
{
    const int fl = *flagp;
    const int rm = decode(rCode, fl);
    const int om = decode(oCode, fl);
    const int r = blockIdx.x, tid = threadIdx.x;
    const size_t o = (size_t)r * 256 + tid;
    float x = toF(A[o]) + ldF(R, o, rm);
    __shared__ float red[256];
    red[tid] = x;
    __syncthreads();
    for (int st = 128; st > 0; st >>= 1) {
        if (tid < st) red[tid] += red[tid + st];
        __syncthreads();
    }
    float mean = red[0] * (1.f / 256.f);
    __syncthreads();
    float dx = x - mean;
    red[tid] = dx * dx;
    __syncthreads();
    for (int st = 128; st > 0; st >>= 1) {
        if (tid < st) red[tid] += red[tid + st];
        __syncthreads();
    }
    float var = red[0] * (1.f / 256.f);
    float y = dx * rsqrtf(var + 1e-5f) * ldF(w, tid, fl) + ldF(b, tid, fl);
    stF(out, o, om, y);
}

// ---------------------------------------------------------------------------
// V transpose with zero pad: V[(ki,b)][hd] -> VT[(b*256+hd)][lkp], cols
// [Lk, lkp) zeroed. Total = 2048*lkp elems, grid = total/256 exactly.
// ---------------------------------------------------------------------------
__global__ __launch_bounds__(256) void transpose_v_kernel(
    const bf16* __restrict__ V, int vs0, int vs1,
    bf16* __restrict__ VT, int Lk, int lkp)
{
    int i = blockIdx.x * 256 + threadIdx.x;  // i = ch*lkp + kp
    int kp = i % lkp;
    int ch = i / lkp;
    int b = ch >> 8, hd = ch & 255;
    bf16 v = __float2bfloat16(0.f);
    if (kp < Lk) v = V[(size_t)kp * vs0 + (size_t)b * vs1 + hd];
    VT[i] = v;
}

// ---------------------------------------------------------------------------
// MFMA flash attention (unchanged from R6; harness-verified).
// ---------------------------------------------------------------------------
__global__ __launch_bounds__(256) void fattn_kernel(
    const bf16* __restrict__ Q, int qs0, int qs1,
    const bf16* __restrict__ K, int ks0, int ks1,
    const bf16* __restrict__ VT, int lkp,
    bf16* __restrict__ O, int Lk, float scale)
{
    const int bh = blockIdx.x;
    const int b = bh >> 3, h = bh & 7;
    const int qt = blockIdx.y;
    const int tid = threadIdx.x;
    const int w = tid >> 6;
    const int lane = tid & 63;
    const int l15 = lane & 15;
    const int quad = lane >> 4;

    __shared__ short Pl[4][16][72];

    const int q0 = qt * 64 + w * 16;
    const int qr = min(q0 + l15, 899);
    short8 aq = *(const short8*)(Q + (size_t)qr * qs0 + (size_t)b * qs1 + h * 32 + quad * 8);

    f32x4 accO0 = {}, accO1 = {};
    float mrow[4] = {-1e30f, -1e30f, -1e30f, -1e30f};
    float lrow[4] = {0.f, 0.f, 0.f, 0.f};

    const bf16* Kb = K + (size_t)b * ks1 + h * 32 + quad * 8;
    const bf16* VTb = VT + (size_t)(b * 256 + h * 32) * lkp;

    const int nkt = (Lk + 63) >> 6;
    for (int kt = 0; kt < nkt; kt++) {
        const int k0 = kt * 64;
        float sv[4][4];
#pragma unroll
        for (int nt = 0; nt < 4; nt++) {
            int kk = k0 + nt * 16 + l15;
            int krow = min(kk, Lk - 1);
            short8 bk = *(const short8*)(Kb + (size_t)krow * ks0);
            f32x4 z = {};
            f32x4 s = __builtin_amdgcn_mfma_f32_16x16x32_bf16(aq, bk, z, 0, 0, 0);
            bool ok = kk < Lk;
#pragma unroll
            for (int r = 0; r < 4; r++) sv[nt][r] = ok ? s[r] * scale : -1e30f;
        }
        float mnew[4], fr[4];
#pragma unroll
        for (int r = 0; r < 4; r++) {
            float t = fmaxf(fmaxf(sv[0][r], sv[1][r]), fmaxf(sv[2][r], sv[3][r]));
            t = fmaxf(t, __shfl_xor(t, 1));
            t = fmaxf(t, __shfl_xor(t, 2));
            t = fmaxf(t, __shfl_xor(t, 4));
            t = fmaxf(t, __shfl_xor(t, 8));
            mnew[r] = fmaxf(mrow[r], t);
            fr[r] = __expf(mrow[r] - mnew[r]);
            mrow[r] = mnew[r];
        }
#pragma unroll
        for (int r = 0; r < 4; r++) {
            float p0 = __expf(sv[0][r] - mnew[r]);
            float p1 = __expf(sv[1][r] - mnew[r]);
            float p2 = __expf(sv[2][r] - mnew[r]);
            float p3 = __expf(sv[3][r] - mnew[r]);
            int row = quad * 4 + r;
            Pl[w][row][l15]      = f2b(p0);
            Pl[w][row][16 + l15] = f2b(p1);
            Pl[w][row][32 + l15] = f2b(p2);
            Pl[w][row][48 + l15] = f2b(p3);
            float t = p0 + p1 + p2 + p3;
            t += __shfl_xor(t, 1);
            t += __shfl_xor(t, 2);
            t += __shfl_xor(t, 4);
            t += __shfl_xor(t, 8);
            lrow[r] = lrow[r] * fr[r] + t;
            accO0[r] *= fr[r];
            accO1[r] *= fr[r];
        }
#pragma unroll
        for (int kt2 = 0; kt2 < 2; kt2++) {
            short8 pa = *(const short8*)&Pl[w][l15][kt2 * 32 + quad * 8];
            short8 v0 = *(const short8*)(VTb + (size_t)l15 * lkp + k0 + kt2 * 32 + quad * 8);
            short8 v1 = *(const short8*)(VTb + (size_t)(16 + l15) * lkp + k0 + kt2 * 32 + quad * 8);
            accO0 = __builtin_amdgcn_mfma_f32_16x16x32_bf16(pa, v0, accO0, 0, 0, 0);
            accO1 = __builtin_amdgcn_mfma_f32_16x16x32_bf16(pa, v1, accO1, 0, 0, 0);
        }
    }
#pragma unroll
    for (int r = 0; r < 4; r++) {
        int q = q0 + quad * 4 + r;
        if (q < 900) {
            float inv = 1.f / lrow[r];
            size_t o = ((size_t)q * 8 + b) * 256 + h * 32;
            O[o + l15]      = __float2bfloat16(accO0[r] * inv);
            O[o + 16 + l15] = __float2bfloat16(accO1[r] * inv);
        }
    }
}

// ---------------------------------------------------------------------------
// Deformable sampling, ALL batches in one dispatch (7200 blocks).
// r = blockIdx.x = qi*8 + b; per-batch val slice = val + (r&7)*21760*256.
// ---------------------------------------------------------------------------
__device__ __forceinline__ float sample_one(const bf16* __restrict__ val,
                                            int base, int HW, int yi, int xi,
                                            int hd32)
{
    bool valid = (xi >= 0) && (xi < HW) && (yi >= 0) && (yi < HW);
    int ix = min(max(xi, 0), HW - 1);
    int iy = min(max(yi, 0), HW - 1);
    size_t idx = (size_t)(base + iy * HW + ix) * 256 + hd32;
    float v = toF(val[idx]);
    return valid ? v : 0.f;
}

__global__ __launch_bounds__(256) void deform_kernel(
    const bf16* __restrict__ val,
    const bf16* __restrict__ off,
    const bf16* __restrict__ awl,
    const void* __restrict__ refp,
    bf16* __restrict__ samp, const int* __restrict__ flagp)
{
    const int fl = *flagp;
    const int levH[4] = {128, 64, 32, 16};
    const int levS[4] = {0, 16384, 20480, 21504};
    const int r = blockIdx.x;
    const int tid = threadIdx.x;
    const int h = tid >> 5, d = tid & 31;
    const int hd32 = h * 32 + d;

    const bf16* valb = val + (size_t)(r & 7) * 5570560;  // 21760*256

    const bf16* lg = awl + (size_t)r * 128 + h * 16;
    float w[16];
    float mx = -1e30f;
#pragma unroll
    for (int i = 0; i < 16; i++) { w[i] = toF(lg[i]); mx = fmaxf(mx, w[i]); }
    float sm = 0.f;
#pragma unroll
    for (int i = 0; i < 16; i++) { w[i] = expf(w[i] - mx); sm += w[i]; }
    float inv = 1.f / sm;

    const bf16* offr = off + (size_t)r * 256 + h * 32;
    float acc = 0.f;
#pragma unroll
    for (int l = 0; l < 4; l++) {
        const int HW = levH[l];
        const int base = levS[l];
        float rx = ldF(refp, (size_t)r * 16 + l * 4 + 0, fl);
        float ry = ldF(refp, (size_t)r * 16 + l * 4 + 1, fl);
        float rw = ldF(refp, (size_t)r * 16 + l * 4 + 2, fl);
        float rh = ldF(refp, (size_t)r * 16 + l * 4 + 3, fl);
#pragma unroll
        for (int p = 0; p < 4; p++) {
            float ox = toF(offr[l * 8 + p * 2 + 0]);
            float oy = toF(offr[l * 8 + p * 2 + 1]);
            float locx = rx + ox * 0.125f * rw;   // off/NP * wh * 0.5
            float locy = ry + oy * 0.125f * rh;
            float x = locx * HW - 0.5f;
            float y = locy * HW - 0.5f;
            float x0f = floorf(x), y0f = floorf(y);
            int x0 = (int)x0f, y0 = (int)y0f;
            float fx = x - x0f, fy = y - y0f;
            float wgt = w[l * 4 + p] * inv;
            float s00 = sample_one(valb, base, HW, y0,     x0,     hd32);
            float s01 = sample_one(valb, base, HW, y0,     x0 + 1, hd32);
            float s10 = sample_one(valb, base, HW, y0 + 1, x0,     hd32);
            float s11 = sample_one(valb, base, HW, y0 + 1, x0 + 1, hd32);
            acc += wgt * (s00 * (1.f - fx) * (1.f - fy) + s01 * fx * (1.f - fy) +
                          s10 * (1.f - fx) * fy + s11 * fx * fy);
        }
    }
    samp[(size_t)r * 256 + tid] = __float2bfloat16(acc);
}

// ---------------------------------------------------------------------------
extern "C" void kernel_launch(void* const* d_in, const int* in_sizes, int n_in,
                              void* d_out, int out_size, void* d_ws, size_t ws_size,
                              hipStream_t stream)
{
    (void)in_sizes; (void)n_in;
    const void* tgt      = d_in[0];
    const void* tgt_pos  = d_in[1];
    const void* refp     = d_in[2];
    const void* mem_sup  = d_in[3];
    const void* memory   = d_in[4];
    const void* sa_in_w  = d_in[6];
    const void* sa_in_b  = d_in[7];
    const void* sa_out_w = d_in[8];
    const void* sa_out_b = d_in[9];
    const void* cs_in_w  = d_in[10];
    const void* cs_in_b  = d_in[11];
    const void* cs_out_w = d_in[12];
    const void* cs_out_b = d_in[13];
    const void* so_w = d_in[14];
    const void* so_b = d_in[15];
    const void* aw_w = d_in[16];
    const void* aw_b = d_in[17];
    const void* vp_w = d_in[18];
    const void* vp_b = d_in[19];
    const void* op_w = d_in[20];
    const void* op_b = d_in[21];
    const void* n1w = d_in[22];
    const void* n1b = d_in[23];
    const void* n2w = d_in[24];
    const void* n2b = d_in[25];
    const void* csnw = d_in[26];
    const void* csnb = d_in[27];
    const void* n3w = d_in[28];
    const void* n3b = d_in[29];
    const void* l1w = d_in[30];
    const void* l1b = d_in[31];
    const void* l2w = d_in[32];
    const void* l2b = d_in[33];

    const int S = 900 * 8 * 256;
    const size_t NEEDED = 133496836;
    const dim3 blk(256);

    if (ws_size < NEEDED) {
        dbg_kernel<<<(out_size + 255) / 256, blk, 0, stream>>>(
            (bf16*)d_out, out_size, (float)(ws_size >> 20));
        return;
    }

    char* base = (char*)d_ws;
    float* T5 = (float*)base;               // [S] f32
    bf16* B1  = (bf16*)(base + 7372800);    // [S]
    bf16* B2  = (bf16*)(base + 11059200);   // [2S]
    bf16* B3  = (bf16*)(base + 18432000);   // [S + 64K elems]
    bf16* B4  = (bf16*)(base + 22249472);   // [S]
    bf16* B5  = (bf16*)(base + 25935872);   // [S]
    bf16* VAL = (bf16*)(base + 29622272);   // [8 * 21760 * 256]
    bf16* H   = (bf16*)(base + 118751232);  // [7200 * 1024]
    int* FL   = (int*)(base + 133496832);

    const float scale = 0.1767766953f;  // 1/sqrt(32)
    const int MT = 7200;
    const int gy = 113;  // ceil(7200/64)

    detect_kernel<<<1, blk, 0, stream>>>((const unsigned short*)tgt, FL);

    // ---- self attention (Lk=900, LkPad=960; VT in T5 region, dead pre-LN) ----
    add_kernel<<<MT, blk, 0, stream>>>(tgt, 2, tgt_pos, B1, S, FL);
    mgemm_kernel<false><<<dim3(8, gy), blk, 0, stream>>>(
        B1, 256, 0, 0, sa_in_w, 0, sa_in_b, 0, B2, 512, MT, 512, 256, 0, 0, FL);  // q,k
    mgemm_kernel<false><<<dim3(4, gy), blk, 0, stream>>>(
        tgt, 256, 0, 2, sa_in_w, 131072, sa_in_b, 512, B3, 256, MT, 256, 256, 0, 0, FL);  // v
    transpose_v_kernel<<<7680, blk, 0, stream>>>(B3, 2048, 256, (bf16*)T5, 900, 960);
    fattn_kernel<<<dim3(64, 15), blk, 0, stream>>>(
        B2, 4096, 512, B2 + 256, 4096, 512, (bf16*)T5, 960, B4, 900, scale);
    mgemm_kernel<false><<<dim3(4, gy), blk, 0, stream>>>(
        B4, 256, 0, 0, sa_out_w, 0, sa_out_b, 0, B5, 256, MT, 256, 256, 0, 0, FL);
    ln_res_kernel<<<MT, blk, 0, stream>>>(B5, tgt, 2, n2w, n2b, T5, 1, FL);

    // ---- cross attention (memory_support, Lk=100, LkPad=128; VT in B1) ----
    add_kernel<<<MT, blk, 0, stream>>>(T5, 1, tgt_pos, B1, S, FL);
    mgemm_kernel<false><<<dim3(4, gy), blk, 0, stream>>>(
        B1, 256, 0, 0, cs_in_w, 0, cs_in_b, 0, B2, 256, MT, 256, 256, 0, 0, FL);  // q
    mgemm_kernel<false><<<dim3(8, 13), blk, 0, stream>>>(
        mem_sup, 256, 0, 2, cs_in_w, 65536, cs_in_b, 256, B3, 512, 800, 512, 256, 0, 0, FL);  // k,v
    transpose_v_kernel<<<1024, blk, 0, stream>>>(B3 + 256, 512, 51200, B1, 100, 128);
    fattn_kernel<<<dim3(64, 15), blk, 0, stream>>>(
        B2, 2048, 256, B3, 512, 51200, B1, 128, B4, 100, scale);
    mgemm_kernel<false><<<dim3(4, gy), blk, 0, stream>>>(
        B4, 256, 0, 0, cs_out_w, 0, cs_out_b, 0, B5, 256, MT, 256, 256, 0, 0, FL);
    ln_res_kernel<<<MT, blk, 0, stream>>>(B5, T5, 1, csnw, csnb, T5, 1, FL);

    // ---- deformable attention ----
    add_kernel<<<MT, blk, 0, stream>>>(T5, 1, tgt_pos, B1, S, FL);  // query
    mgemm_kernel<false><<<dim3(4, gy), blk, 0, stream>>>(
        B1, 256, 0, 0, so_w, 0, so_b, 0, B4, 256, MT, 256, 256, 0, 0, FL);       // offsets
    mgemm_kernel<false><<<dim3(2, gy), blk, 0, stream>>>(
        B1, 256, 0, 0, aw_w, 0, aw_b, 0, B5, 128, MT, 128, 256, 0, 0, FL);       // aw logits
    // val proj, all 8 batches in one dispatch (z = batch)
    mgemm_kernel<false><<<dim3(4, 340, 8), blk, 0, stream>>>(
        memory, 2048, 0, 2, vp_w, 0, vp_b, 0, VAL, 256,
        21760, 256, 256, 256, 5570560, FL);
    deform_kernel<<<7200, blk, 0, stream>>>(VAL, B4, B5, refp, B1, FL);
    mgemm_kernel<false><<<dim3(4, gy), blk, 0, stream>>>(
        B1, 256, 0, 0, op_w, 0, op_b, 0, B5, 256, MT, 256, 256, 0, 0, FL);       // out proj
    ln_res_kernel<<<MT, blk, 0, stream>>>(B5, T5, 1, n1w, n1b, T5, 1, FL);

    // ---- FFN (single-shot via H buffer) ----
    mgemm_kernel<true><<<dim3(16, gy), blk, 0, stream>>>(
        T5, 256, 0, 1, l1w, 0, l1b, 0, H, 1024, MT, 1024, 256, 0, 0, FL);
    mgemm_kernel<false><<<dim3(4, gy), blk, 0, stream>>>(
        H, 1024, 0, 0, l2w, 0, l2b, 0, B5, 256, MT, 256, 1024, 0, 0, FL);
    ln_res_kernel<<<MT, blk, 0, stream>>>(B5, T5, 1, n3w, n3b, d_out, 2, FL);
}

// Round 5
// 1116.296 us; speedup vs baseline: 2.3437x; 1.1421x over previous
//
#include <hip/hip_runtime.h>
#include <hip/hip_bf16.h>

// DeformableTransformerDecoderLayer on MI355X — Round 8.
// R7: 1274 us. val-proj mgemm = 445 us, FETCH 350 MB (2x ideal), MfmaUtil 2%,
// VALU 12%, HBM 13% -> nothing saturated; cost is the x-grid's 4x re-read of
// the f32 A rows + 4x the W-frag load instructions per output element.
// This round: mgemm_wide_kernel, block = 64(M) x 256(N), wave w owns cols
// w*64..+64, acc[4][4]; A read once (memory as flat [174080][256] rows,
// VAL stored in [ki*8+b] row order; deform row stride 256 -> 2048). Wide
// kernel replaces all N>=256 GEMMs (A-dup x4-x16 removed); aw (N=128) keeps
// the old kernel.
//   E=256 NH=8 HD=32 NL=4 NP=4 DFFN=1024, nq=900 bs=8 Ls=100 Lv=21760.
//
// Arena (byte offsets), S = 7200*256 = 1,843,200 elems:
//   T5 f32 [S]        @ 0            running tgt | self VT (pre-LN scratch)
//   B1 bf16 [S]       @ 7,372,800    q=tgt(+pos) | cross VT | deform samp
//   B2 bf16 [2S]      @ 11,059,200   self QK | cross q
//   B3 bf16 [S+64K]   @ 18,432,000   self V | cross KV
//   B4 bf16 [S]       @ 22,249,472   attn out | deform off
//   B5 bf16 [S]       @ 25,935,872   proj out | deform awl
//   VAL bf16 [174080*256] @ 29,622,272   projected value, row = ki*8+b
//   H  bf16 [7200*1024]   @ 118,751,232  FFN hidden
//   FLAG int          @ 133,496,832  detected input dtype (1=f32, 0=bf16)
// NEEDED = 133,496,836 bytes (ws ~713 MB per poison fill size).

typedef __hip_bfloat16 bf16;
typedef __attribute__((ext_vector_type(8))) short short8;
typedef __attribute__((ext_vector_type(4))) float f32x4;

__device__ __forceinline__ float toF(bf16 x) { return __bfloat162float(x); }

__device__ __forceinline__ float ldF(const void* p, size_t i, int f32mode) {
    if (f32mode) return ((const float*)p)[i];
    return __bfloat162float(((const bf16*)p)[i]);
}
__device__ __forceinline__ void stF(void* p, size_t i, int f32mode, float v) {
    if (f32mode) ((float*)p)[i] = v;
    else ((bf16*)p)[i] = __float2bfloat16(v);
}
// mode codes: 0 = bf16 (ws), 1 = f32 (ws), 2 = external (use flag)
__device__ __forceinline__ int decode(int code, int fl) { return code == 2 ? fl : code; }

__device__ __forceinline__ short f2b(float x) {
    bf16 h = __float2bfloat16(x);
    return *(short*)&h;
}

// Load 8 consecutive elements starting at element idx as a bf16x8 fragment.
__device__ __forceinline__ short8 loadFrag8(const void* p, size_t idx, int f32m) {
    short8 r;
    if (f32m) {
        const float4* q = (const float4*)((const float*)p + idx);
        float4 u = q[0];
        float4 v = q[1];
        r[0] = f2b(u.x); r[1] = f2b(u.y); r[2] = f2b(u.z); r[3] = f2b(u.w);
        r[4] = f2b(v.x); r[5] = f2b(v.y); r[6] = f2b(v.z); r[7] = f2b(v.w);
    } else {
        r = *(const short8*)((const bf16*)p + idx);
    }
    return r;
}

// ---------------------------------------------------------------------------
// Input dtype detector (unchanged).
// ---------------------------------------------------------------------------
__global__ __launch_bounds__(256) void detect_kernel(
    const unsigned short* __restrict__ t, int* __restrict__ flag)
{
    __shared__ int bad;
    if (threadIdx.x == 0) bad = 0;
    __syncthreads();
    int my = 0;
    for (int k = 0; k < 8; k++) {
        unsigned u = t[threadIdx.x + 256 * k];
        unsigned e = (u >> 7) & 0xFF;
        if (e >= 0xC0) my = 1;
    }
    if (my) atomicOr(&bad, 1);
    __syncthreads();
    if (threadIdx.x == 0) *flag = bad;
}

__global__ __launch_bounds__(256) void dbg_kernel(bf16* out, int n, float v)
{
    int i = blockIdx.x * 256 + threadIdx.x;
    if (i < n) out[i] = __float2bfloat16(v);
}

// ---------------------------------------------------------------------------
// Narrow MFMA GEMM (N=128 case only now): block 64x64, wave -> 16x64.
// ---------------------------------------------------------------------------
template <bool RELU>
__global__ __launch_bounds__(256) void mgemm_kernel(
    const void* __restrict__ A, int lda, size_t aOff, int aCode,
    const void* __restrict__ W, size_t wOff,
    const void* __restrict__ bias, size_t bOff,
    bf16* __restrict__ C, int ldc,
    int M, int N, int K, const int* __restrict__ flagp)
{
    const int fl = *flagp;
    const int am = decode(aCode, fl);
    const int tid = threadIdx.x;
    const int lane = tid & 63;
    const int wv = tid >> 6;
    const int l15 = lane & 15;
    const int quad = lane >> 4;
    const int bm = blockIdx.y * 64 + wv * 16;
    const int bn = blockIdx.x * 64;

    const int ar = min(bm + l15, M - 1);  // clamped A row (stores predicated)
    const size_t aBase = aOff + (size_t)ar * lda + quad * 8;

    f32x4 acc[4] = {};

    for (int k0 = 0; k0 < K; k0 += 32) {
        short8 af = loadFrag8(A, aBase + k0, am);
#pragma unroll
        for (int nt = 0; nt < 4; nt++) {
            int n = bn + nt * 16 + l15;
            short8 bfr = loadFrag8(W, wOff + (size_t)n * K + quad * 8 + k0, fl);
            acc[nt] = __builtin_amdgcn_mfma_f32_16x16x32_bf16(af, bfr, acc[nt], 0, 0, 0);
        }
    }

#pragma unroll
    for (int nt = 0; nt < 4; nt++) {
        int n = bn + nt * 16 + l15;
        float bv = ldF(bias, bOff + n, fl);
#pragma unroll
        for (int r = 0; r < 4; r++) {
            int row = bm + quad * 4 + r;
            if (row < M) {
                float v = acc[nt][r] + bv;
                if (RELU) v = fmaxf(v, 0.f);
                C[(size_t)row * ldc + n] = __float2bfloat16(v);
            }
        }
    }
}

// ---------------------------------------------------------------------------
// Wide MFMA GEMM: block = 64(M) x 256(N); wave w owns cols w*64..+64;
// acc[mt][nt] (4x4 f32x4 = 64 VGPR). A-tile shared by all 4 waves (L1-hit
// after first), W-frag loads per output element cut 4x vs narrow kernel.
// Grid: (N/256, ceil(M/64)). Row clamp + predicated store as before.
// ---------------------------------------------------------------------------
template <bool RELU>
__global__ __launch_bounds__(256) void mgemm_wide_kernel(
    const void* __restrict__ A, int lda, size_t aOff, int aCode,
    const void* __restrict__ W, size_t wOff,
    const void* __restrict__ bias, size_t bOff,
    bf16* __restrict__ C, int ldc,
    int M, int K, const int* __restrict__ flagp)
{
    const int fl = *flagp;
    const int am = decode(aCode, fl);
    const int tid = threadIdx.x;
    const int lane = tid & 63;
    const int w = tid >> 6;
    const int l15 = lane & 15;
    const int quad = lane >> 4;
    const int bm = blockIdx.y * 64;
    const int bn = blockIdx.x * 256 + w * 64;

    f32x4 acc[4][4] = {};

    for (int k0 = 0; k0 < K; k0 += 32) {
        short8 af[4];
#pragma unroll
        for (int mt = 0; mt < 4; mt++) {
            int ar = min(bm + mt * 16 + l15, M - 1);
            af[mt] = loadFrag8(A, aOff + (size_t)ar * lda + quad * 8 + k0, am);
        }
#pragma unroll
        for (int nt = 0; nt < 4; nt++) {
            int n = bn + nt * 16 + l15;
            short8 bfr = loadFrag8(W, wOff + (size_t)n * K + quad * 8 + k0, fl);
#pragma unroll
            for (int mt = 0; mt < 4; mt++) {
                acc[mt][nt] = __builtin_amdgcn_mfma_f32_16x16x32_bf16(
                    af[mt], bfr, acc[mt][nt], 0, 0, 0);
            }
        }
    }

#pragma unroll
    for (int nt = 0; nt < 4; nt++) {
        int n = bn + nt * 16 + l15;
        float bv = ldF(bias, bOff + n, fl);
#pragma unroll
        for (int mt = 0; mt < 4; mt++) {
#pragma unroll
            for (int r = 0; r < 4; r++) {
                int row = bm + mt * 16 + quad * 4 + r;
                if (row < M) {
                    float v = acc[mt][nt][r] + bv;
                    if (RELU) v = fmaxf(v, 0.f);
                    C[(size_t)row * ldc + n] = __float2bfloat16(v);
                }
            }
        }
    }
}

// ---------------------------------------------------------------------------
__global__ __launch_bounds__(256) void add_kernel(
    const void* __restrict__ A, int aCode, const void* __restrict__ B,
    bf16* __restrict__ out, int n, const int* __restrict__ flagp)
{
    const int fl = *flagp;
    const int am = decode(aCode, fl);
    int i = blockIdx.x * 256 + threadIdx.x;
    if (i < n) out[i] = __float2bfloat16(ldF(A, i, am) + ldF(B, i, fl));
}

// ---------------------------------------------------------------------------
// Fused residual + LayerNorm over E=256 (unchanged).
// ---------------------------------------------------------------------------
__global__ __launch_bounds__(256) void ln_res_kernel(
    const bf16* __restrict__ A, const void* __restrict__ R, int rCode,
    const void* __restrict__ w, const void* __restrict__ b,
    void* __restrict__ out, int oCode, const int* __restrict__ flagp)
{
    const int fl = *flagp;
    const int rm = decode(rCode, fl);
    const int om = decode(oCode, fl);
    const int r = blockIdx.x, tid = threadIdx.x;
    const size_t o = (size_t)r * 256 + tid;
    float x = toF(A[o]) + ldF(R, o, rm);
    __shared__ float red[256];
    red[tid] = x;
    __syncthreads();
    for (int st = 128; st > 0; st >>= 1) {
        if (tid < st) red[tid] += red[tid + st];
        __syncthreads();
    }
    float mean = red[0] * (1.f / 256.f);
    __syncthreads();
    float dx = x - mean;
    red[tid] = dx * dx;
    __syncthreads();
    for (int st = 128; st > 0; st >>= 1) {
        if (tid < st) red[tid] += red[tid + st];
        __syncthreads();
    }
    float var = red[0] * (1.f / 256.f);
    float y = dx * rsqrtf(var + 1e-5f) * ldF(w, tid, fl) + ldF(b, tid, fl);
    stF(out, o, om, y);
}

// ---------------------------------------------------------------------------
// V transpose with zero pad: V[(ki,b)][hd] -> VT[(b*256+hd)][lkp], cols
// [Lk, lkp) zeroed. Total = 2048*lkp elems, grid = total/256 exactly.
// ---------------------------------------------------------------------------
__global__ __launch_bounds__(256) void transpose_v_kernel(
    const bf16* __restrict__ V, int vs0, int vs1,
    bf16* __restrict__ VT, int Lk, int lkp)
{
    int i = blockIdx.x * 256 + threadIdx.x;  // i = ch*lkp + kp
    int kp = i % lkp;
    int ch = i / lkp;
    int b = ch >> 8, hd = ch & 255;
    bf16 v = __float2bfloat16(0.f);
    if (kp < Lk) v = V[(size_t)kp * vs0 + (size_t)b * vs1 + hd];
    VT[i] = v;
}

// ---------------------------------------------------------------------------
// MFMA flash attention (unchanged; harness-verified).
// ---------------------------------------------------------------------------
__global__ __launch_bounds__(256) void fattn_kernel(
    const bf16* __restrict__ Q, int qs0, int qs1,
    const bf16* __restrict__ K, int ks0, int ks1,
    const bf16* __restrict__ VT, int lkp,
    bf16* __restrict__ O, int Lk, float scale)
{
    const int bh = blockIdx.x;
    const int b = bh >> 3, h = bh & 7;
    const int qt = blockIdx.y;
    const int tid = threadIdx.x;
    const int w = tid >> 6;
    const int lane = tid & 63;
    const int l15 = lane & 15;
    const int quad = lane >> 4;

    __shared__ short Pl[4][16][72];

    const int q0 = qt * 64 + w * 16;
    const int qr = min(q0 + l15, 899);
    short8 aq = *(const short8*)(Q + (size_t)qr * qs0 + (size_t)b * qs1 + h * 32 + quad * 8);

    f32x4 accO0 = {}, accO1 = {};
    float mrow[4] = {-1e30f, -1e30f, -1e30f, -1e30f};
    float lrow[4] = {0.f, 0.f, 0.f, 0.f};

    const bf16* Kb = K + (size_t)b * ks1 + h * 32 + quad * 8;
    const bf16* VTb = VT + (size_t)(b * 256 + h * 32) * lkp;

    const int nkt = (Lk + 63) >> 6;
    for (int kt = 0; kt < nkt; kt++) {
        const int k0 = kt * 64;
        float sv[4][4];
#pragma unroll
        for (int nt = 0; nt < 4; nt++) {
            int kk = k0 + nt * 16 + l15;
            int krow = min(kk, Lk - 1);
            short8 bk = *(const short8*)(Kb + (size_t)krow * ks0);
            f32x4 z = {};
            f32x4 s = __builtin_amdgcn_mfma_f32_16x16x32_bf16(aq, bk, z, 0, 0, 0);
            bool ok = kk < Lk;
#pragma unroll
            for (int r = 0; r < 4; r++) sv[nt][r] = ok ? s[r] * scale : -1e30f;
        }
        float mnew[4], fr[4];
#pragma unroll
        for (int r = 0; r < 4; r++) {
            float t = fmaxf(fmaxf(sv[0][r], sv[1][r]), fmaxf(sv[2][r], sv[3][r]));
            t = fmaxf(t, __shfl_xor(t, 1));
            t = fmaxf(t, __shfl_xor(t, 2));
            t = fmaxf(t, __shfl_xor(t, 4));
            t = fmaxf(t, __shfl_xor(t, 8));
            mnew[r] = fmaxf(mrow[r], t);
            fr[r] = __expf(mrow[r] - mnew[r]);
            mrow[r] = mnew[r];
        }
#pragma unroll
        for (int r = 0; r < 4; r++) {
            float p0 = __expf(sv[0][r] - mnew[r]);
            float p1 = __expf(sv[1][r] - mnew[r]);
            float p2 = __expf(sv[2][r] - mnew[r]);
            float p3 = __expf(sv[3][r] - mnew[r]);
            int row = quad * 4 + r;
            Pl[w][row][l15]      = f2b(p0);
            Pl[w][row][16 + l15] = f2b(p1);
            Pl[w][row][32 + l15] = f2b(p2);
            Pl[w][row][48 + l15] = f2b(p3);
            float t = p0 + p1 + p2 + p3;
            t += __shfl_xor(t, 1);
            t += __shfl_xor(t, 2);
            t += __shfl_xor(t, 4);
            t += __shfl_xor(t, 8);
            lrow[r] = lrow[r] * fr[r] + t;
            accO0[r] *= fr[r];
            accO1[r] *= fr[r];
        }
#pragma unroll
        for (int kt2 = 0; kt2 < 2; kt2++) {
            short8 pa = *(const short8*)&Pl[w][l15][kt2 * 32 + quad * 8];
            short8 v0 = *(const short8*)(VTb + (size_t)l15 * lkp + k0 + kt2 * 32 + quad * 8);
            short8 v1 = *(const short8*)(VTb + (size_t)(16 + l15) * lkp + k0 + kt2 * 32 + quad * 8);
            accO0 = __builtin_amdgcn_mfma_f32_16x16x32_bf16(pa, v0, accO0, 0, 0, 0);
            accO1 = __builtin_amdgcn_mfma_f32_16x16x32_bf16(pa, v1, accO1, 0, 0, 0);
        }
    }
#pragma unroll
    for (int r = 0; r < 4; r++) {
        int q = q0 + quad * 4 + r;
        if (q < 900) {
            float inv = 1.f / lrow[r];
            size_t o = ((size_t)q * 8 + b) * 256 + h * 32;
            O[o + l15]      = __float2bfloat16(accO0[r] * inv);
            O[o + 16 + l15] = __float2bfloat16(accO1[r] * inv);
        }
    }
}

// ---------------------------------------------------------------------------
// Deformable sampling, all batches, 7200 blocks. VAL rows are [ki*8+b][256]
// (row stride 2048 elems per spatial index; +b*256 base).
// ---------------------------------------------------------------------------
__device__ __forceinline__ float sample_one(const bf16* __restrict__ valb,
                                            int base, int HW, int yi, int xi,
                                            int hd32)
{
    bool valid = (xi >= 0) && (xi < HW) && (yi >= 0) && (yi < HW);
    int ix = min(max(xi, 0), HW - 1);
    int iy = min(max(yi, 0), HW - 1);
    size_t idx = (size_t)(base + iy * HW + ix) * 2048 + hd32;
    float v = toF(valb[idx]);
    return valid ? v : 0.f;
}

__global__ __launch_bounds__(256) void deform_kernel(
    const bf16* __restrict__ val,
    const bf16* __restrict__ off,
    const bf16* __restrict__ awl,
    const void* __restrict__ refp,
    bf16* __restrict__ samp, const int* __restrict__ flagp)
{
    const int fl = *flagp;
    const int levH[4] = {128, 64, 32, 16};
    const int levS[4] = {0, 16384, 20480, 21504};
    const int r = blockIdx.x;
    const int tid = threadIdx.x;
    const int h = tid >> 5, d = tid & 31;
    const int hd32 = h * 32 + d;

    const bf16* valb = val + (size_t)(r & 7) * 256;

    const bf16* lg = awl + (size_t)r * 128 + h * 16;
    float w[16];
    float mx = -1e30f;
#pragma unroll
    for (int i = 0; i < 16; i++) { w[i] = toF(lg[i]); mx = fmaxf(mx, w[i]); }
    float sm = 0.f;
#pragma unroll
    for (int i = 0; i < 16; i++) { w[i] = expf(w[i] - mx); sm += w[i]; }
    float inv = 1.f / sm;

    const bf16* offr = off + (size_t)r * 256 + h * 32;
    float acc = 0.f;
#pragma unroll
    for (int l = 0; l < 4; l++) {
        const int HW = levH[l];
        const int base = levS[l];
        float rx = ldF(refp, (size_t)r * 16 + l * 4 + 0, fl);
        float ry = ldF(refp, (size_t)r * 16 + l * 4 + 1, fl);
        float rw = ldF(refp, (size_t)r * 16 + l * 4 + 2, fl);
        float rh = ldF(refp, (size_t)r * 16 + l * 4 + 3, fl);
#pragma unroll
        for (int p = 0; p < 4; p++) {
            float ox = toF(offr[l * 8 + p * 2 + 0]);
            float oy = toF(offr[l * 8 + p * 2 + 1]);
            float locx = rx + ox * 0.125f * rw;   // off/NP * wh * 0.5
            float locy = ry + oy * 0.125f * rh;
            float x = locx * HW - 0.5f;
            float y = locy * HW - 0.5f;
            float x0f = floorf(x), y0f = floorf(y);
            int x0 = (int)x0f, y0 = (int)y0f;
            float fx = x - x0f, fy = y - y0f;
            float wgt = w[l * 4 + p] * inv;
            float s00 = sample_one(valb, base, HW, y0,     x0,     hd32);
            float s01 = sample_one(valb, base, HW, y0,     x0 + 1, hd32);
            float s10 = sample_one(valb, base, HW, y0 + 1, x0,     hd32);
            float s11 = sample_one(valb, base, HW, y0 + 1, x0 + 1, hd32);
            acc += wgt * (s00 * (1.f - fx) * (1.f - fy) + s01 * fx * (1.f - fy) +
                          s10 * (1.f - fx) * fy + s11 * fx * fy);
        }
    }
    samp[(size_t)r * 256 + tid] = __float2bfloat16(acc);
}

// ---------------------------------------------------------------------------
extern "C" void kernel_launch(void* const* d_in, const int* in_sizes, int n_in,
                              void* d_out, int out_size, void* d_ws, size_t ws_size,
                              hipStream_t stream)
{
    (void)in_sizes; (void)n_in;
    const void* tgt      = d_in[0];
    const void* tgt_pos  = d_in[1];
    const void* refp     = d_in[2];
    const void* mem_sup  = d_in[3];
    const void* memory   = d_in[4];
    const void* sa_in_w  = d_in[6];
    const void* sa_in_b  = d_in[7];
    const void* sa_out_w = d_in[8];
    const void* sa_out_b = d_in[9];
    const void* cs_in_w  = d_in[10];
    const void* cs_in_b  = d_in[11];
    const void* cs_out_w = d_in[12];
    const void* cs_out_b = d_in[13];
    const void* so_w = d_in[14];
    const void* so_b = d_in[15];
    const void* aw_w = d_in[16];
    const void* aw_b = d_in[17];
    const void* vp_w = d_in[18];
    const void* vp_b = d_in[19];
    const void* op_w = d_in[20];
    const void* op_b = d_in[21];
    const void* n1w = d_in[22];
    const void* n1b = d_in[23];
    const void* n2w = d_in[24];
    const void* n2b = d_in[25];
    const void* csnw = d_in[26];
    const void* csnb = d_in[27];
    const void* n3w = d_in[28];
    const void* n3b = d_in[29];
    const void* l1w = d_in[30];
    const void* l1b = d_in[31];
    const void* l2w = d_in[32];
    const void* l2b = d_in[33];

    const int S = 900 * 8 * 256;
    const size_t NEEDED = 133496836;
    const dim3 blk(256);

    if (ws_size < NEEDED) {
        dbg_kernel<<<(out_size + 255) / 256, blk, 0, stream>>>(
            (bf16*)d_out, out_size, (float)(ws_size >> 20));
        return;
    }

    char* base = (char*)d_ws;
    float* T5 = (float*)base;               // [S] f32
    bf16* B1  = (bf16*)(base + 7372800);    // [S]
    bf16* B2  = (bf16*)(base + 11059200);   // [2S]
    bf16* B3  = (bf16*)(base + 18432000);   // [S + 64K elems]
    bf16* B4  = (bf16*)(base + 22249472);   // [S]
    bf16* B5  = (bf16*)(base + 25935872);   // [S]
    bf16* VAL = (bf16*)(base + 29622272);   // [174080 * 256], row = ki*8+b
    bf16* H   = (bf16*)(base + 118751232);  // [7200 * 1024]
    int* FL   = (int*)(base + 133496832);

    const float scale = 0.1767766953f;  // 1/sqrt(32)
    const int MT = 7200;
    const int gy = 113;  // ceil(7200/64)

    detect_kernel<<<1, blk, 0, stream>>>((const unsigned short*)tgt, FL);

    // ---- self attention (Lk=900, LkPad=960; VT in T5 region, dead pre-LN) ----
    add_kernel<<<MT, blk, 0, stream>>>(tgt, 2, tgt_pos, B1, S, FL);
    mgemm_wide_kernel<false><<<dim3(2, gy), blk, 0, stream>>>(
        B1, 256, 0, 0, sa_in_w, 0, sa_in_b, 0, B2, 512, MT, 256, FL);        // q,k
    mgemm_wide_kernel<false><<<dim3(1, gy), blk, 0, stream>>>(
        tgt, 256, 0, 2, sa_in_w, 131072, sa_in_b, 512, B3, 256, MT, 256, FL); // v
    transpose_v_kernel<<<7680, blk, 0, stream>>>(B3, 2048, 256, (bf16*)T5, 900, 960);
    fattn_kernel<<<dim3(64, 15), blk, 0, stream>>>(
        B2, 4096, 512, B2 + 256, 4096, 512, (bf16*)T5, 960, B4, 900, scale);
    mgemm_wide_kernel<false><<<dim3(1, gy), blk, 0, stream>>>(
        B4, 256, 0, 0, sa_out_w, 0, sa_out_b, 0, B5, 256, MT, 256, FL);
    ln_res_kernel<<<MT, blk, 0, stream>>>(B5, tgt, 2, n2w, n2b, T5, 1, FL);

    // ---- cross attention (memory_support, Lk=100, LkPad=128; VT in B1) ----
    add_kernel<<<MT, blk, 0, stream>>>(T5, 1, tgt_pos, B1, S, FL);
    mgemm_wide_kernel<false><<<dim3(1, gy), blk, 0, stream>>>(
        B1, 256, 0, 0, cs_in_w, 0, cs_in_b, 0, B2, 256, MT, 256, FL);        // q
    mgemm_wide_kernel<false><<<dim3(2, 13), blk, 0, stream>>>(
        mem_sup, 256, 0, 2, cs_in_w, 65536, cs_in_b, 256, B3, 512, 800, 256, FL);  // k,v
    transpose_v_kernel<<<1024, blk, 0, stream>>>(B3 + 256, 512, 51200, B1, 100, 128);
    fattn_kernel<<<dim3(64, 15), blk, 0, stream>>>(
        B2, 2048, 256, B3, 512, 51200, B1, 128, B4, 100, scale);
    mgemm_wide_kernel<false><<<dim3(1, gy), blk, 0, stream>>>(
        B4, 256, 0, 0, cs_out_w, 0, cs_out_b, 0, B5, 256, MT, 256, FL);
    ln_res_kernel<<<MT, blk, 0, stream>>>(B5, T5, 1, csnw, csnb, T5, 1, FL);

    // ---- deformable attention ----
    add_kernel<<<MT, blk, 0, stream>>>(T5, 1, tgt_pos, B1, S, FL);  // query
    mgemm_wide_kernel<false><<<dim3(1, gy), blk, 0, stream>>>(
        B1, 256, 0, 0, so_w, 0, so_b, 0, B4, 256, MT, 256, FL);              // offsets
    mgemm_kernel<false><<<dim3(2, gy), blk, 0, stream>>>(
        B1, 256, 0, 0, aw_w, 0, aw_b, 0, B5, 128, MT, 128, 256, FL);         // aw logits
    // val proj: memory as flat [174080][256] rows; VAL rows = ki*8+b
    mgemm_wide_kernel<false><<<dim3(1, 2720), blk, 0, stream>>>(
        memory, 256, 0, 2, vp_w, 0, vp_b, 0, VAL, 256, 174080, 256, FL);
    deform_kernel<<<7200, blk, 0, stream>>>(VAL, B4, B5, refp, B1, FL);
    mgemm_wide_kernel<false><<<dim3(1, gy), blk, 0, stream>>>(
        B1, 256, 0, 0, op_w, 0, op_b, 0, B5, 256, MT, 256, FL);              // out proj
    ln_res_kernel<<<MT, blk, 0, stream>>>(B5, T5, 1, n1w, n1b, T5, 1, FL);

    // ---- FFN (single-shot via H buffer) ----
    mgemm_wide_kernel<true><<<dim3(4, gy), blk, 0, stream>>>(
        T5, 256, 0, 1, l1w, 0, l1b, 0, H, 1024, MT, 256, FL);
    mgemm_wide_kernel<false><<<dim3(1, gy), blk, 0, stream>>>(
        H, 1024, 0, 0, l2w, 0, l2b, 0, B5, 256, MT, 1024, FL);
    ln_res_kernel<<<MT, blk, 0, stream>>>(B5, T5, 1, n3w, n3b, d_out, 2, FL);
}

// Round 7
// 927.878 us; speedup vs baseline: 2.8196x; 1.2031x over previous
//
#include <hip/hip_runtime.h>
#include <hip/hip_bf16.h>

// DeformableTransformerDecoderLayer on MI355X — Round 9 (resubmit; R9 bench
// hit an infra failure — container died twice, no counters; same as R1 which
// passed unchanged on resubmit. Source audited: LDS 30.7 KB, staging
// coverage exact, bounds/alignment checked).
// R8: 1116 us. Wide GEMM: occupancy 31% (136 regs), WRITE 187 MB vs 89 MB
// written (=> ~98 MB spill write-back), HBM pinned ~1.1 TB/s, MfmaUtil 3.6%.
// Diagnosis: dual-mode loadFrag8 unrolled x8 over a 64-AGPR accumulator
// spills; 2.5 waves/SIMD can't hide scratch+HBM latency.
// This round: LDS-staged GEMM (guide §5): 512 thr / 8 waves, tile
// 128Mx256Nx32K; A staged once per block (not per wave), dtype branch out of
// the inner loop; frags via ds_read_b128 from padded [row][40] LDS (16B-
// aligned, 2-way alias = free). Wave (wr,wc) owns 64x64; acc[4][4].
// Replaces all N>=256 GEMMs; aw (N=128) keeps narrow kernel.
//   E=256 NH=8 HD=32 NL=4 NP=4 DFFN=1024, nq=900 bs=8 Ls=100 Lv=21760.
//
// Arena (byte offsets), S = 7200*256 = 1,843,200 elems:
//   T5 f32 [S]        @ 0            running tgt | self VT (pre-LN scratch)
//   B1 bf16 [S]       @ 7,372,800    q=tgt(+pos) | cross VT | deform samp
//   B2 bf16 [2S]      @ 11,059,200   self QK | cross q
//   B3 bf16 [S+64K]   @ 18,432,000   self V | cross KV
//   B4 bf16 [S]       @ 22,249,472   attn out | deform off
//   B5 bf16 [S]       @ 25,935,872   proj out | deform awl
//   VAL bf16 [174080*256] @ 29,622,272   projected value, row = ki*8+b
//   H  bf16 [7200*1024]   @ 118,751,232  FFN hidden
//   FLAG int          @ 133,496,832  detected input dtype (1=f32, 0=bf16)
// NEEDED = 133,496,836 bytes (ws ~713 MB per poison fill size).

typedef __hip_bfloat16 bf16;
typedef __attribute__((ext_vector_type(8))) short short8;
typedef __attribute__((ext_vector_type(4))) float f32x4;

__device__ __forceinline__ float toF(bf16 x) { return __bfloat162float(x); }

__device__ __forceinline__ float ldF(const void* p, size_t i, int f32mode) {
    if (f32mode) return ((const float*)p)[i];
    return __bfloat162float(((const bf16*)p)[i]);
}
__device__ __forceinline__ void stF(void* p, size_t i, int f32mode, float v) {
    if (f32mode) ((float*)p)[i] = v;
    else ((bf16*)p)[i] = __float2bfloat16(v);
}
// mode codes: 0 = bf16 (ws), 1 = f32 (ws), 2 = external (use flag)
__device__ __forceinline__ int decode(int code, int fl) { return code == 2 ? fl : code; }

__device__ __forceinline__ short f2b(float x) {
    bf16 h = __float2bfloat16(x);
    return *(short*)&h;
}

// Load 8 consecutive elements starting at element idx as a bf16x8 fragment.
__device__ __forceinline__ short8 loadFrag8(const void* p, size_t idx, int f32m) {
    short8 r;
    if (f32m) {
        const float4* q = (const float4*)((const float*)p + idx);
        float4 u = q[0];
        float4 v = q[1];
        r[0] = f2b(u.x); r[1] = f2b(u.y); r[2] = f2b(u.z); r[3] = f2b(u.w);
        r[4] = f2b(v.x); r[5] = f2b(v.y); r[6] = f2b(v.z); r[7] = f2b(v.w);
    } else {
        r = *(const short8*)((const bf16*)p + idx);
    }
    return r;
}

// ---------------------------------------------------------------------------
// Input dtype detector (unchanged).
// ---------------------------------------------------------------------------
__global__ __launch_bounds__(256) void detect_kernel(
    const unsigned short* __restrict__ t, int* __restrict__ flag)
{
    __shared__ int bad;
    if (threadIdx.x == 0) bad = 0;
    __syncthreads();
    int my = 0;
    for (int k = 0; k < 8; k++) {
        unsigned u = t[threadIdx.x + 256 * k];
        unsigned e = (u >> 7) & 0xFF;
        if (e >= 0xC0) my = 1;
    }
    if (my) atomicOr(&bad, 1);
    __syncthreads();
    if (threadIdx.x == 0) *flag = bad;
}

__global__ __launch_bounds__(256) void dbg_kernel(bf16* out, int n, float v)
{
    int i = blockIdx.x * 256 + threadIdx.x;
    if (i < n) out[i] = __float2bfloat16(v);
}

// ---------------------------------------------------------------------------
// Narrow MFMA GEMM (N=128 aw case only): block 64x64, wave -> 16x64.
// ---------------------------------------------------------------------------
template <bool RELU>
__global__ __launch_bounds__(256) void mgemm_kernel(
    const void* __restrict__ A, int lda, size_t aOff, int aCode,
    const void* __restrict__ W, size_t wOff,
    const void* __restrict__ bias, size_t bOff,
    bf16* __restrict__ C, int ldc,
    int M, int N, int K, const int* __restrict__ flagp)
{
    const int fl = *flagp;
    const int am = decode(aCode, fl);
    const int tid = threadIdx.x;
    const int lane = tid & 63;
    const int wv = tid >> 6;
    const int l15 = lane & 15;
    const int quad = lane >> 4;
    const int bm = blockIdx.y * 64 + wv * 16;
    const int bn = blockIdx.x * 64;

    const int ar = min(bm + l15, M - 1);  // clamped A row (stores predicated)
    const size_t aBase = aOff + (size_t)ar * lda + quad * 8;

    f32x4 acc[4] = {};

    for (int k0 = 0; k0 < K; k0 += 32) {
        short8 af = loadFrag8(A, aBase + k0, am);
#pragma unroll
        for (int nt = 0; nt < 4; nt++) {
            int n = bn + nt * 16 + l15;
            short8 bfr = loadFrag8(W, wOff + (size_t)n * K + quad * 8 + k0, fl);
            acc[nt] = __builtin_amdgcn_mfma_f32_16x16x32_bf16(af, bfr, acc[nt], 0, 0, 0);
        }
    }

#pragma unroll
    for (int nt = 0; nt < 4; nt++) {
        int n = bn + nt * 16 + l15;
        float bv = ldF(bias, bOff + n, fl);
#pragma unroll
        for (int r = 0; r < 4; r++) {
            int row = bm + quad * 4 + r;
            if (row < M) {
                float v = acc[nt][r] + bv;
                if (RELU) v = fmaxf(v, 0.f);
                C[(size_t)row * ldc + n] = __float2bfloat16(v);
            }
        }
    }
}

// ---------------------------------------------------------------------------
// LDS-staged MFMA GEMM: 512 thr = 8 waves; block tile 128(M) x 256(N);
// K-step 32. Wave (wr=w>>2, wc=w&3) owns rows wr*64..+64, cols wc*64..+64,
// acc[4][4]. Per K-step: cooperative stage A[128][32]+W[256][32] into padded
// LDS [row][40] (80 B stride: every row 16B-aligned; 2-way bank alias free),
// then 8 ds_read_b128 + 16 MFMA per wave. Dtype branch runs in staging only.
// Grid: (N/256, ceil(M/128)). N % 256 == 0, K % 32 == 0; M arbitrary.
// ---------------------------------------------------------------------------
template <bool RELU>
__global__ __launch_bounds__(512) void mgemm_lds_kernel(
    const void* __restrict__ A, int lda, size_t aOff, int aCode,
    const void* __restrict__ W, size_t wOff,
    const void* __restrict__ bias, size_t bOff,
    bf16* __restrict__ C, int ldc,
    int M, int K, const int* __restrict__ flagp)
{
    const int fl = *flagp;
    const int am = decode(aCode, fl);
    const int tid = threadIdx.x;
    const int lane = tid & 63;
    const int w = tid >> 6;           // 0..7
    const int l15 = lane & 15;
    const int quad = lane >> 4;
    const int wr = w >> 2;            // 0..1
    const int wc = w & 3;             // 0..3
    const int bm = blockIdx.y * 128;
    const int bn = blockIdx.x * 256;

    __shared__ short Al[128][40];
    __shared__ short Bl[256][40];

    // staging maps: A = 512 slots of 8 elems; B = 1024 slots (2 per thread)
    const int sRow = tid >> 2;          // 0..127
    const int sCb  = (tid & 3) * 8;     // 0,8,16,24
    const int gArow = min(bm + sRow, M - 1);
    const size_t aRowBase = aOff + (size_t)gArow * lda + sCb;
    const size_t wRowBase0 = wOff + (size_t)(bn + sRow) * K + sCb;
    const size_t wRowBase1 = wOff + (size_t)(bn + 128 + sRow) * K + sCb;

    f32x4 acc[4][4] = {};

    for (int k0 = 0; k0 < K; k0 += 32) {
        __syncthreads();  // prior-step readers done before overwrite
        *(short8*)&Al[sRow][sCb]       = loadFrag8(A, aRowBase + k0, am);
        *(short8*)&Bl[sRow][sCb]       = loadFrag8(W, wRowBase0 + k0, fl);
        *(short8*)&Bl[128 + sRow][sCb] = loadFrag8(W, wRowBase1 + k0, fl);
        __syncthreads();

        short8 a0 = *(const short8*)&Al[wr * 64 +  0 + l15][quad * 8];
        short8 a1 = *(const short8*)&Al[wr * 64 + 16 + l15][quad * 8];
        short8 a2 = *(const short8*)&Al[wr * 64 + 32 + l15][quad * 8];
        short8 a3 = *(const short8*)&Al[wr * 64 + 48 + l15][quad * 8];
#pragma unroll
        for (int nt = 0; nt < 4; nt++) {
            short8 b = *(const short8*)&Bl[wc * 64 + nt * 16 + l15][quad * 8];
            acc[0][nt] = __builtin_amdgcn_mfma_f32_16x16x32_bf16(a0, b, acc[0][nt], 0, 0, 0);
            acc[1][nt] = __builtin_amdgcn_mfma_f32_16x16x32_bf16(a1, b, acc[1][nt], 0, 0, 0);
            acc[2][nt] = __builtin_amdgcn_mfma_f32_16x16x32_bf16(a2, b, acc[2][nt], 0, 0, 0);
            acc[3][nt] = __builtin_amdgcn_mfma_f32_16x16x32_bf16(a3, b, acc[3][nt], 0, 0, 0);
        }
    }

#pragma unroll
    for (int nt = 0; nt < 4; nt++) {
        int n = bn + wc * 64 + nt * 16 + l15;
        float bv = ldF(bias, bOff + n, fl);
#pragma unroll
        for (int mt = 0; mt < 4; mt++) {
#pragma unroll
            for (int r = 0; r < 4; r++) {
                int row = bm + wr * 64 + mt * 16 + quad * 4 + r;
                if (row < M) {
                    float v = acc[mt][nt][r] + bv;
                    if (RELU) v = fmaxf(v, 0.f);
                    C[(size_t)row * ldc + n] = __float2bfloat16(v);
                }
            }
        }
    }
}

// ---------------------------------------------------------------------------
__global__ __launch_bounds__(256) void add_kernel(
    const void* __restrict__ A, int aCode, const void* __restrict__ B,
    bf16* __restrict__ out, int n, const int* __restrict__ flagp)
{
    const int fl = *flagp;
    const int am = decode(aCode, fl);
    int i = blockIdx.x * 256 + threadIdx.x;
    if (i < n) out[i] = __float2bfloat16(ldF(A, i, am) + ldF(B, i, fl));
}

// ---------------------------------------------------------------------------
// Fused residual + LayerNorm over E=256 (unchanged).
// ---------------------------------------------------------------------------
__global__ __launch_bounds__(256) void ln_res_kernel(
    const bf16* __restrict__ A, const void* __restrict__ R, int rCode,
    const void* __restrict__ w, const void* __restrict__ b,
    void* __restrict__ out, int oCode, const int* __restrict__ flagp)
{
    const int fl = *flagp;
    const int rm = decode(rCode, fl);
    const int om = decode(oCode, fl);
    const int r = blockIdx.x, tid = threadIdx.x;
    const size_t o = (size_t)r * 256 + tid;
    float x = toF(A[o]) + ldF(R, o, rm);
    __shared__ float red[256];
    red[tid] = x;
    __syncthreads();
    for (int st = 128; st > 0; st >>= 1) {
        if (tid < st) red[tid] += red[tid + st];
        __syncthreads();
    }
    float mean = red[0] * (1.f / 256.f);
    __syncthreads();
    float dx = x - mean;
    red[tid] = dx * dx;
    __syncthreads();
    for (int st = 128; st > 0; st >>= 1) {
        if (tid < st) red[tid] += red[tid + st];
        __syncthreads();
    }
    float var = red[0] * (1.f / 256.f);
    float y = dx * rsqrtf(var + 1e-5f) * ldF(w, tid, fl) + ldF(b, tid, fl);
    stF(out, o, om, y);
}

// ---------------------------------------------------------------------------
// V transpose with zero pad: V[(ki,b)][hd] -> VT[(b*256+hd)][lkp], cols
// [Lk, lkp) zeroed. Total = 2048*lkp elems, grid = total/256 exactly.
// ---------------------------------------------------------------------------
__global__ __launch_bounds__(256) void transpose_v_kernel(
    const bf16* __restrict__ V, int vs0, int vs1,
    bf16* __restrict__ VT, int Lk, int lkp)
{
    int i = blockIdx.x * 256 + threadIdx.x;  // i = ch*lkp + kp
    int kp = i % lkp;
    int ch = i / lkp;
    int b = ch >> 8, hd = ch & 255;
    bf16 v = __float2bfloat16(0.f);
    if (kp < Lk) v = V[(size_t)kp * vs0 + (size_t)b * vs1 + hd];
    VT[i] = v;
}

// ---------------------------------------------------------------------------
// MFMA flash attention (unchanged; harness-verified).
// ---------------------------------------------------------------------------
__global__ __launch_bounds__(256) void fattn_kernel(
    const bf16* __restrict__ Q, int qs0, int qs1,
    const bf16* __restrict__ K, int ks0, int ks1,
    const bf16* __restrict__ VT, int lkp,
    bf16* __restrict__ O, int Lk, float scale)
{
    const int bh = blockIdx.x;
    const int b = bh >> 3, h = bh & 7;
    const int qt = blockIdx.y;
    const int tid = threadIdx.x;
    const int w = tid >> 6;
    const int lane = tid & 63;
    const int l15 = lane & 15;
    const int quad = lane >> 4;

    __shared__ short Pl[4][16][72];

    const int q0 = qt * 64 + w * 16;
    const int qr = min(q0 + l15, 899);
    short8 aq = *(const short8*)(Q + (size_t)qr * qs0 + (size_t)b * qs1 + h * 32 + quad * 8);

    f32x4 accO0 = {}, accO1 = {};
    float mrow[4] = {-1e30f, -1e30f, -1e30f, -1e30f};
    float lrow[4] = {0.f, 0.f, 0.f, 0.f};

    const bf16* Kb = K + (size_t)b * ks1 + h * 32 + quad * 8;
    const bf16* VTb = VT + (size_t)(b * 256 + h * 32) * lkp;

    const int nkt = (Lk + 63) >> 6;
    for (int kt = 0; kt < nkt; kt++) {
        const int k0 = kt * 64;
        float sv[4][4];
#pragma unroll
        for (int nt = 0; nt < 4; nt++) {
            int kk = k0 + nt * 16 + l15;
            int krow = min(kk, Lk - 1);
            short8 bk = *(const short8*)(Kb + (size_t)krow * ks0);
            f32x4 z = {};
            f32x4 s = __builtin_amdgcn_mfma_f32_16x16x32_bf16(aq, bk, z, 0, 0, 0);
            bool ok = kk < Lk;
#pragma unroll
            for (int r = 0; r < 4; r++) sv[nt][r] = ok ? s[r] * scale : -1e30f;
        }
        float mnew[4], fr[4];
#pragma unroll
        for (int r = 0; r < 4; r++) {
            float t = fmaxf(fmaxf(sv[0][r], sv[1][r]), fmaxf(sv[2][r], sv[3][r]));
            t = fmaxf(t, __shfl_xor(t, 1));
            t = fmaxf(t, __shfl_xor(t, 2));
            t = fmaxf(t, __shfl_xor(t, 4));
            t = fmaxf(t, __shfl_xor(t, 8));
            mnew[r] = fmaxf(mrow[r], t);
            fr[r] = __expf(mrow[r] - mnew[r]);
            mrow[r] = mnew[r];
        }
#pragma unroll
        for (int r = 0; r < 4; r++) {
            float p0 = __expf(sv[0][r] - mnew[r]);
            float p1 = __expf(sv[1][r] - mnew[r]);
            float p2 = __expf(sv[2][r] - mnew[r]);
            float p3 = __expf(sv[3][r] - mnew[r]);
            int row = quad * 4 + r;
            Pl[w][row][l15]      = f2b(p0);
            Pl[w][row][16 + l15] = f2b(p1);
            Pl[w][row][32 + l15] = f2b(p2);
            Pl[w][row][48 + l15] = f2b(p3);
            float t = p0 + p1 + p2 + p3;
            t += __shfl_xor(t, 1);
            t += __shfl_xor(t, 2);
            t += __shfl_xor(t, 4);
            t += __shfl_xor(t, 8);
            lrow[r] = lrow[r] * fr[r] + t;
            accO0[r] *= fr[r];
            accO1[r] *= fr[r];
        }
#pragma unroll
        for (int kt2 = 0; kt2 < 2; kt2++) {
            short8 pa = *(const short8*)&Pl[w][l15][kt2 * 32 + quad * 8];
            short8 v0 = *(const short8*)(VTb + (size_t)l15 * lkp + k0 + kt2 * 32 + quad * 8);
            short8 v1 = *(const short8*)(VTb + (size_t)(16 + l15) * lkp + k0 + kt2 * 32 + quad * 8);
            accO0 = __builtin_amdgcn_mfma_f32_16x16x32_bf16(pa, v0, accO0, 0, 0, 0);
            accO1 = __builtin_amdgcn_mfma_f32_16x16x32_bf16(pa, v1, accO1, 0, 0, 0);
        }
    }
#pragma unroll
    for (int r = 0; r < 4; r++) {
        int q = q0 + quad * 4 + r;
        if (q < 900) {
            float inv = 1.f / lrow[r];
            size_t o = ((size_t)q * 8 + b) * 256 + h * 32;
            O[o + l15]      = __float2bfloat16(accO0[r] * inv);
            O[o + 16 + l15] = __float2bfloat16(accO1[r] * inv);
        }
    }
}

// ---------------------------------------------------------------------------
// Deformable sampling, all batches, 7200 blocks. VAL rows are [ki*8+b][256]
// (row stride 2048 elems per spatial index; +b*256 base).
// ---------------------------------------------------------------------------
__device__ __forceinline__ float sample_one(const bf16* __restrict__ valb,
                                            int base, int HW, int yi, int xi,
                                            int hd32)
{
    bool valid = (xi >= 0) && (xi < HW) && (yi >= 0) && (yi < HW);
    int ix = min(max(xi, 0), HW - 1);
    int iy = min(max(yi, 0), HW - 1);
    size_t idx = (size_t)(base + iy * HW + ix) * 2048 + hd32;
    float v = toF(valb[idx]);
    return valid ? v : 0.f;
}

__global__ __launch_bounds__(256) void deform_kernel(
    const bf16* __restrict__ val,
    const bf16* __restrict__ off,
    const bf16* __restrict__ awl,
    const void* __restrict__ refp,
    bf16* __restrict__ samp, const int* __restrict__ flagp)
{
    const int fl = *flagp;
    const int levH[4] = {128, 64, 32, 16};
    const int levS[4] = {0, 16384, 20480, 21504};
    const int r = blockIdx.x;
    const int tid = threadIdx.x;
    const int h = tid >> 5, d = tid & 31;
    const int hd32 = h * 32 + d;

    const bf16* valb = val + (size_t)(r & 7) * 256;

    const bf16* lg = awl + (size_t)r * 128 + h * 16;
    float w[16];
    float mx = -1e30f;
#pragma unroll
    for (int i = 0; i < 16; i++) { w[i] = toF(lg[i]); mx = fmaxf(mx, w[i]); }
    float sm = 0.f;
#pragma unroll
    for (int i = 0; i < 16; i++) { w[i] = expf(w[i] - mx); sm += w[i]; }
    float inv = 1.f / sm;

    const bf16* offr = off + (size_t)r * 256 + h * 32;
    float acc = 0.f;
#pragma unroll
    for (int l = 0; l < 4; l++) {
        const int HW = levH[l];
        const int base = levS[l];
        float rx = ldF(refp, (size_t)r * 16 + l * 4 + 0, fl);
        float ry = ldF(refp, (size_t)r * 16 + l * 4 + 1, fl);
        float rw = ldF(refp, (size_t)r * 16 + l * 4 + 2, fl);
        float rh = ldF(refp, (size_t)r * 16 + l * 4 + 3, fl);
#pragma unroll
        for (int p = 0; p < 4; p++) {
            float ox = toF(offr[l * 8 + p * 2 + 0]);
            float oy = toF(offr[l * 8 + p * 2 + 1]);
            float locx = rx + ox * 0.125f * rw;   // off/NP * wh * 0.5
            float locy = ry + oy * 0.125f * rh;
            float x = locx * HW - 0.5f;
            float y = locy * HW - 0.5f;
            float x0f = floorf(x), y0f = floorf(y);
            int x0 = (int)x0f, y0 = (int)y0f;
            float fx = x - x0f, fy = y - y0f;
            float wgt = w[l * 4 + p] * inv;
            float s00 = sample_one(valb, base, HW, y0,     x0,     hd32);
            float s01 = sample_one(valb, base, HW, y0,     x0 + 1, hd32);
            float s10 = sample_one(valb, base, HW, y0 + 1, x0,     hd32);
            float s11 = sample_one(valb, base, HW, y0 + 1, x0 + 1, hd32);
            acc += wgt * (s00 * (1.f - fx) * (1.f - fy) + s01 * fx * (1.f - fy) +
                          s10 * (1.f - fx) * fy + s11 * fx * fy);
        }
    }
    samp[(size_t)r * 256 + tid] = __float2bfloat16(acc);
}

// ---------------------------------------------------------------------------
extern "C" void kernel_launch(void* const* d_in, const int* in_sizes, int n_in,
                              void* d_out, int out_size, void* d_ws, size_t ws_size,
                              hipStream_t stream)
{
    (void)in_sizes; (void)n_in;
    const void* tgt      = d_in[0];
    const void* tgt_pos  = d_in[1];
    const void* refp     = d_in[2];
    const void* mem_sup  = d_in[3];
    const void* memory   = d_in[4];
    const void* sa_in_w  = d_in[6];
    const void* sa_in_b  = d_in[7];
    const void* sa_out_w = d_in[8];
    const void* sa_out_b = d_in[9];
    const void* cs_in_w  = d_in[10];
    const void* cs_in_b  = d_in[11];
    const void* cs_out_w = d_in[12];
    const void* cs_out_b = d_in[13];
    const void* so_w = d_in[14];
    const void* so_b = d_in[15];
    const void* aw_w = d_in[16];
    const void* aw_b = d_in[17];
    const void* vp_w = d_in[18];
    const void* vp_b = d_in[19];
    const void* op_w = d_in[20];
    const void* op_b = d_in[21];
    const void* n1w = d_in[22];
    const void* n1b = d_in[23];
    const void* n2w = d_in[24];
    const void* n2b = d_in[25];
    const void* csnw = d_in[26];
    const void* csnb = d_in[27];
    const void* n3w = d_in[28];
    const void* n3b = d_in[29];
    const void* l1w = d_in[30];
    const void* l1b = d_in[31];
    const void* l2w = d_in[32];
    const void* l2b = d_in[33];

    const int S = 900 * 8 * 256;
    const size_t NEEDED = 133496836;
    const dim3 blk(256);
    const dim3 blk2(512);

    if (ws_size < NEEDED) {
        dbg_kernel<<<(out_size + 255) / 256, blk, 0, stream>>>(
            (bf16*)d_out, out_size, (float)(ws_size >> 20));
        return;
    }

    char* base = (char*)d_ws;
    float* T5 = (float*)base;               // [S] f32
    bf16* B1  = (bf16*)(base + 7372800);    // [S]
    bf16* B2  = (bf16*)(base + 11059200);   // [2S]
    bf16* B3  = (bf16*)(base + 18432000);   // [S + 64K elems]
    bf16* B4  = (bf16*)(base + 22249472);   // [S]
    bf16* B5  = (bf16*)(base + 25935872);   // [S]
    bf16* VAL = (bf16*)(base + 29622272);   // [174080 * 256], row = ki*8+b
    bf16* H   = (bf16*)(base + 118751232);  // [7200 * 1024]
    int* FL   = (int*)(base + 133496832);

    const float scale = 0.1767766953f;  // 1/sqrt(32)
    const int MT = 7200;
    const int gy = 57;  // ceil(7200/128)

    detect_kernel<<<1, blk, 0, stream>>>((const unsigned short*)tgt, FL);

    // ---- self attention (Lk=900, LkPad=960; VT in T5 region, dead pre-LN) ----
    add_kernel<<<MT, blk, 0, stream>>>(tgt, 2, tgt_pos, B1, S, FL);
    mgemm_lds_kernel<false><<<dim3(2, gy), blk2, 0, stream>>>(
        B1, 256, 0, 0, sa_in_w, 0, sa_in_b, 0, B2, 512, MT, 256, FL);        // q,k
    mgemm_lds_kernel<false><<<dim3(1, gy), blk2, 0, stream>>>(
        tgt, 256, 0, 2, sa_in_w, 131072, sa_in_b, 512, B3, 256, MT, 256, FL); // v
    transpose_v_kernel<<<7680, blk, 0, stream>>>(B3, 2048, 256, (bf16*)T5, 900, 960);
    fattn_kernel<<<dim3(64, 15), blk, 0, stream>>>(
        B2, 4096, 512, B2 + 256, 4096, 512, (bf16*)T5, 960, B4, 900, scale);
    mgemm_lds_kernel<false><<<dim3(1, gy), blk2, 0, stream>>>(
        B4, 256, 0, 0, sa_out_w, 0, sa_out_b, 0, B5, 256, MT, 256, FL);
    ln_res_kernel<<<MT, blk, 0, stream>>>(B5, tgt, 2, n2w, n2b, T5, 1, FL);

    // ---- cross attention (memory_support, Lk=100, LkPad=128; VT in B1) ----
    add_kernel<<<MT, blk, 0, stream>>>(T5, 1, tgt_pos, B1, S, FL);
    mgemm_lds_kernel<false><<<dim3(1, gy), blk2, 0, stream>>>(
        B1, 256, 0, 0, cs_in_w, 0, cs_in_b, 0, B2, 256, MT, 256, FL);        // q
    mgemm_lds_kernel<false><<<dim3(2, 7), blk2, 0, stream>>>(
        mem_sup, 256, 0, 2, cs_in_w, 65536, cs_in_b, 256, B3, 512, 800, 256, FL);  // k,v
    transpose_v_kernel<<<1024, blk, 0, stream>>>(B3 + 256, 512, 51200, B1, 100, 128);
    fattn_kernel<<<dim3(64, 15), blk, 0, stream>>>(
        B2, 2048, 256, B3, 512, 51200, B1, 128, B4, 100, scale);
    mgemm_lds_kernel<false><<<dim3(1, gy), blk2, 0, stream>>>(
        B4, 256, 0, 0, cs_out_w, 0, cs_out_b, 0, B5, 256, MT, 256, FL);
    ln_res_kernel<<<MT, blk, 0, stream>>>(B5, T5, 1, csnw, csnb, T5, 1, FL);

    // ---- deformable attention ----
    add_kernel<<<MT, blk, 0, stream>>>(T5, 1, tgt_pos, B1, S, FL);  // query
    mgemm_lds_kernel<false><<<dim3(1, gy), blk2, 0, stream>>>(
        B1, 256, 0, 0, so_w, 0, so_b, 0, B4, 256, MT, 256, FL);              // offsets
    mgemm_kernel<false><<<dim3(2, 113), blk, 0, stream>>>(
        B1, 256, 0, 0, aw_w, 0, aw_b, 0, B5, 128, MT, 128, 256, FL);         // aw logits
    // val proj: memory as flat [174080][256] rows; VAL rows = ki*8+b
    mgemm_lds_kernel<false><<<dim3(1, 1360), blk2, 0, stream>>>(
        memory, 256, 0, 2, vp_w, 0, vp_b, 0, VAL, 256, 174080, 256, FL);
    deform_kernel<<<7200, blk, 0, stream>>>(VAL, B4, B5, refp, B1, FL);
    mgemm_lds_kernel<false><<<dim3(1, gy), blk2, 0, stream>>>(
        B1, 256, 0, 0, op_w, 0, op_b, 0, B5, 256, MT, 256, FL);              // out proj
    ln_res_kernel<<<MT, blk, 0, stream>>>(B5, T5, 1, n1w, n1b, T5, 1, FL);

    // ---- FFN (single-shot via H buffer) ----
    mgemm_lds_kernel<true><<<dim3(4, gy), blk2, 0, stream>>>(
        T5, 256, 0, 1, l1w, 0, l1b, 0, H, 1024, MT, 256, FL);
    mgemm_lds_kernel<false><<<dim3(1, gy), blk2, 0, stream>>>(
        H, 1024, 0, 0, l2w, 0, l2b, 0, B5, 256, MT, 1024, FL);
    ln_res_kernel<<<MT, blk, 0, stream>>>(B5, T5, 1, n3w, n3b, d_out, 2, FL);
}

// Round 9
// 842.733 us; speedup vs baseline: 3.1045x; 1.1010x over previous
//
#include <hip/hip_runtime.h>
#include <hip/hip_bf16.h>

// DeformableTransformerDecoderLayer on MI355X — Round 10 (resubmit; R10 bench
// hit the session's third infra failure — container died twice, no counters;
// R1/R6 had the same signature and passed unchanged on resubmit. Source
// audited: staging coverage exact, uniform barriers, 16B alignment, bounds).
// R9: 928 us. val-proj 137 us (WRITE 127 vs 89 MB written: partial-line
// stores). Everything else: ~790 us over ~24 dispatches; all M=7200/N=256
// GEMMs ran at grid (1,57) = 57 blocks = 22% of the 256-CU machine.
// This round: (1) mgemm_lds64 (64Mx128N, 8 waves, wave=16x64, acc[4]=16 AGPR,
// LDS 15.4 KB) for all GEMMs except val-proj -> grids 226-904 blocks; A-dup
// across x-blocks is L2/L3-resident (A <= 14.7 MB) so free. val-proj keeps
// the A-read-once 128x256 kernel (A = 178 MB f32). (2) residual fusion:
// optional R pointer added to A during staging kills all 3 add_kernels.
// (3) epilogue stores nt-innermost -> full-line write combining.
//   E=256 NH=8 HD=32 NL=4 NP=4 DFFN=1024, nq=900 bs=8 Ls=100 Lv=21760.
//
// Arena (byte offsets), S = 7200*256 = 1,843,200 elems:
//   T5 f32 [S]        @ 0            running tgt | self VT (pre-LN scratch)
//   B1 bf16 [S]       @ 7,372,800    cross VT | deform samp
//   B2 bf16 [2S]      @ 11,059,200   self QK | cross q
//   B3 bf16 [S+64K]   @ 18,432,000   self V | cross KV
//   B4 bf16 [S]       @ 22,249,472   attn out | deform off
//   B5 bf16 [S]       @ 25,935,872   proj out | deform awl
//   VAL bf16 [174080*256] @ 29,622,272   projected value, row = ki*8+b
//   H  bf16 [7200*1024]   @ 118,751,232  FFN hidden
//   FLAG int          @ 133,496,832  detected input dtype (1=f32, 0=bf16)
// NEEDED = 133,496,836 bytes (ws ~713 MB per poison fill size).

typedef __hip_bfloat16 bf16;
typedef __attribute__((ext_vector_type(8))) short short8;
typedef __attribute__((ext_vector_type(4))) float f32x4;

__device__ __forceinline__ float toF(bf16 x) { return __bfloat162float(x); }

__device__ __forceinline__ float ldF(const void* p, size_t i, int f32mode) {
    if (f32mode) return ((const float*)p)[i];
    return __bfloat162float(((const bf16*)p)[i]);
}
__device__ __forceinline__ void stF(void* p, size_t i, int f32mode, float v) {
    if (f32mode) ((float*)p)[i] = v;
    else ((bf16*)p)[i] = __float2bfloat16(v);
}
// mode codes: 0 = bf16 (ws), 1 = f32 (ws), 2 = external (use flag)
__device__ __forceinline__ int decode(int code, int fl) { return code == 2 ? fl : code; }

__device__ __forceinline__ short f2b(float x) {
    bf16 h = __float2bfloat16(x);
    return *(short*)&h;
}

// Load 8 consecutive elements starting at element idx as a bf16x8 fragment.
__device__ __forceinline__ short8 loadFrag8(const void* p, size_t idx, int f32m) {
    short8 r;
    if (f32m) {
        const float4* q = (const float4*)((const float*)p + idx);
        float4 u = q[0];
        float4 v = q[1];
        r[0] = f2b(u.x); r[1] = f2b(u.y); r[2] = f2b(u.z); r[3] = f2b(u.w);
        r[4] = f2b(v.x); r[5] = f2b(v.y); r[6] = f2b(v.z); r[7] = f2b(v.w);
    } else {
        r = *(const short8*)((const bf16*)p + idx);
    }
    return r;
}

// Fused A+R load (R = residual/positional, same [row][256] layout, idx shared).
// Used only in staging (once per element); null R -> plain vector path.
__device__ __forceinline__ short8 loadFragF(const void* A, size_t ia, int am,
                                            const void* R, int rm) {
    if (R == nullptr) return loadFrag8(A, ia, am);
    short8 o;
#pragma unroll
    for (int j = 0; j < 8; j++) o[j] = f2b(ldF(A, ia + j, am) + ldF(R, ia + j, rm));
    return o;
}

// ---------------------------------------------------------------------------
// Input dtype detector (unchanged).
// ---------------------------------------------------------------------------
__global__ __launch_bounds__(256) void detect_kernel(
    const unsigned short* __restrict__ t, int* __restrict__ flag)
{
    __shared__ int bad;
    if (threadIdx.x == 0) bad = 0;
    __syncthreads();
    int my = 0;
    for (int k = 0; k < 8; k++) {
        unsigned u = t[threadIdx.x + 256 * k];
        unsigned e = (u >> 7) & 0xFF;
        if (e >= 0xC0) my = 1;
    }
    if (my) atomicOr(&bad, 1);
    __syncthreads();
    if (threadIdx.x == 0) *flag = bad;
}

__global__ __launch_bounds__(256) void dbg_kernel(bf16* out, int n, float v)
{
    int i = blockIdx.x * 256 + threadIdx.x;
    if (i < n) out[i] = __float2bfloat16(v);
}

// ---------------------------------------------------------------------------
// LDS-staged MFMA GEMM, 128(M) x 256(N) tile — val-proj only (A read once).
// 512 thr / 8 waves; wave (wr=w>>2, wc=w&3) owns 64x64; acc[4][4].
// ---------------------------------------------------------------------------
template <bool RELU>
__global__ __launch_bounds__(512) void mgemm_lds_kernel(
    const void* __restrict__ A, int lda, size_t aOff, int aCode,
    const void* __restrict__ W, size_t wOff,
    const void* __restrict__ bias, size_t bOff,
    bf16* __restrict__ C, int ldc,
    int M, int K, const int* __restrict__ flagp)
{
    const int fl = *flagp;
    const int am = decode(aCode, fl);
    const int tid = threadIdx.x;
    const int lane = tid & 63;
    const int w = tid >> 6;
    const int l15 = lane & 15;
    const int quad = lane >> 4;
    const int wr = w >> 2;
    const int wc = w & 3;
    const int bm = blockIdx.y * 128;
    const int bn = blockIdx.x * 256;

    __shared__ short Al[128][40];
    __shared__ short Bl[256][40];

    const int sRow = tid >> 2;
    const int sCb  = (tid & 3) * 8;
    const int gArow = min(bm + sRow, M - 1);
    const size_t aRowBase = aOff + (size_t)gArow * lda + sCb;
    const size_t wRowBase0 = wOff + (size_t)(bn + sRow) * K + sCb;
    const size_t wRowBase1 = wOff + (size_t)(bn + 128 + sRow) * K + sCb;

    f32x4 acc[4][4] = {};

    for (int k0 = 0; k0 < K; k0 += 32) {
        __syncthreads();
        *(short8*)&Al[sRow][sCb]       = loadFrag8(A, aRowBase + k0, am);
        *(short8*)&Bl[sRow][sCb]       = loadFrag8(W, wRowBase0 + k0, fl);
        *(short8*)&Bl[128 + sRow][sCb] = loadFrag8(W, wRowBase1 + k0, fl);
        __syncthreads();

        short8 a0 = *(const short8*)&Al[wr * 64 +  0 + l15][quad * 8];
        short8 a1 = *(const short8*)&Al[wr * 64 + 16 + l15][quad * 8];
        short8 a2 = *(const short8*)&Al[wr * 64 + 32 + l15][quad * 8];
        short8 a3 = *(const short8*)&Al[wr * 64 + 48 + l15][quad * 8];
#pragma unroll
        for (int nt = 0; nt < 4; nt++) {
            short8 b = *(const short8*)&Bl[wc * 64 + nt * 16 + l15][quad * 8];
            acc[0][nt] = __builtin_amdgcn_mfma_f32_16x16x32_bf16(a0, b, acc[0][nt], 0, 0, 0);
            acc[1][nt] = __builtin_amdgcn_mfma_f32_16x16x32_bf16(a1, b, acc[1][nt], 0, 0, 0);
            acc[2][nt] = __builtin_amdgcn_mfma_f32_16x16x32_bf16(a2, b, acc[2][nt], 0, 0, 0);
            acc[3][nt] = __builtin_amdgcn_mfma_f32_16x16x32_bf16(a3, b, acc[3][nt], 0, 0, 0);
        }
    }

    // Epilogue: nt innermost -> 4 back-to-back 32B segments per row (full-line
    // write combining; R9 showed WRITE 1.43x actual bytes with nt outermost).
#pragma unroll
    for (int mt = 0; mt < 4; mt++) {
#pragma unroll
        for (int r = 0; r < 4; r++) {
            int row = bm + wr * 64 + mt * 16 + quad * 4 + r;
            if (row < M) {
#pragma unroll
                for (int nt = 0; nt < 4; nt++) {
                    int n = bn + wc * 64 + nt * 16 + l15;
                    float v = acc[mt][nt][r] + ldF(bias, bOff + n, fl);
                    if (RELU) v = fmaxf(v, 0.f);
                    C[(size_t)row * ldc + n] = __float2bfloat16(v);
                }
            }
        }
    }
}

// ---------------------------------------------------------------------------
// LDS-staged MFMA GEMM, 64(M) x 128(N) tile — all other GEMMs.
// 512 thr / 8 waves; wave (wr=w>>1 rows wr*16, wc=w&1 cols wc*64); acc[4]
// (16 AGPR -> high occupancy). Optional fused residual R (A+R staged).
// Grid: (N/128, ceil(M/64)). N % 128 == 0, K % 32 == 0, M arbitrary.
// ---------------------------------------------------------------------------
template <bool RELU>
__global__ __launch_bounds__(512) void mgemm_lds64_kernel(
    const void* __restrict__ A, int lda, size_t aOff, int aCode,
    const void* __restrict__ R, int rCode,
    const void* __restrict__ W, size_t wOff,
    const void* __restrict__ bias, size_t bOff,
    bf16* __restrict__ C, int ldc,
    int M, int K, const int* __restrict__ flagp)
{
    const int fl = *flagp;
    const int am = decode(aCode, fl);
    const int rm = decode(rCode, fl);
    const int tid = threadIdx.x;
    const int lane = tid & 63;
    const int w = tid >> 6;
    const int l15 = lane & 15;
    const int quad = lane >> 4;
    const int wr = w >> 1;            // 0..3 (16-row strips)
    const int wc = w & 1;             // 0..1 (64-col strips)
    const int bm = blockIdx.y * 64;
    const int bn = blockIdx.x * 128;

    __shared__ short Al[64][40];
    __shared__ short Bl[128][40];

    // A: 64x32 = 256 slots (threads 0..255); B: 128x32 = 512 slots (all).
    const int sRow = tid >> 2;          // 0..127
    const int sCb  = (tid & 3) * 8;
    const int gArow = min(bm + (sRow & 63), M - 1);
    const size_t aRowBase = aOff + (size_t)gArow * lda + sCb;
    const size_t wRowBase = wOff + (size_t)(bn + sRow) * K + sCb;

    f32x4 acc[4] = {};

    for (int k0 = 0; k0 < K; k0 += 32) {
        __syncthreads();
        if (tid < 256) {
            *(short8*)&Al[sRow][sCb] = loadFragF(A, aRowBase + k0, am, R, rm);
        }
        *(short8*)&Bl[sRow][sCb] = loadFrag8(W, wRowBase + k0, fl);
        __syncthreads();

        short8 a = *(const short8*)&Al[wr * 16 + l15][quad * 8];
#pragma unroll
        for (int nt = 0; nt < 4; nt++) {
            short8 b = *(const short8*)&Bl[wc * 64 + nt * 16 + l15][quad * 8];
            acc[nt] = __builtin_amdgcn_mfma_f32_16x16x32_bf16(a, b, acc[nt], 0, 0, 0);
        }
    }

#pragma unroll
    for (int r = 0; r < 4; r++) {
        int row = bm + wr * 16 + quad * 4 + r;
        if (row < M) {
#pragma unroll
            for (int nt = 0; nt < 4; nt++) {
                int n = bn + wc * 64 + nt * 16 + l15;
                float v = acc[nt][r] + ldF(bias, bOff + n, fl);
                if (RELU) v = fmaxf(v, 0.f);
                C[(size_t)row * ldc + n] = __float2bfloat16(v);
            }
        }
    }
}

// ---------------------------------------------------------------------------
// Fused residual + LayerNorm over E=256 (unchanged).
// ---------------------------------------------------------------------------
__global__ __launch_bounds__(256) void ln_res_kernel(
    const bf16* __restrict__ A, const void* __restrict__ R, int rCode,
    const void* __restrict__ w, const void* __restrict__ b,
    void* __restrict__ out, int oCode, const int* __restrict__ flagp)
{
    const int fl = *flagp;
    const int rm = decode(rCode, fl);
    const int om = decode(oCode, fl);
    const int r = blockIdx.x, tid = threadIdx.x;
    const size_t o = (size_t)r * 256 + tid;
    float x = toF(A[o]) + ldF(R, o, rm);
    __shared__ float red[256];
    red[tid] = x;
    __syncthreads();
    for (int st = 128; st > 0; st >>= 1) {
        if (tid < st) red[tid] += red[tid + st];
        __syncthreads();
    }
    float mean = red[0] * (1.f / 256.f);
    __syncthreads();
    float dx = x - mean;
    red[tid] = dx * dx;
    __syncthreads();
    for (int st = 128; st > 0; st >>= 1) {
        if (tid < st) red[tid] += red[tid + st];
        __syncthreads();
    }
    float var = red[0] * (1.f / 256.f);
    float y = dx * rsqrtf(var + 1e-5f) * ldF(w, tid, fl) + ldF(b, tid, fl);
    stF(out, o, om, y);
}

// ---------------------------------------------------------------------------
// V transpose with zero pad: V[(ki,b)][hd] -> VT[(b*256+hd)][lkp], cols
// [Lk, lkp) zeroed. Total = 2048*lkp elems, grid = total/256 exactly.
// ---------------------------------------------------------------------------
__global__ __launch_bounds__(256) void transpose_v_kernel(
    const bf16* __restrict__ V, int vs0, int vs1,
    bf16* __restrict__ VT, int Lk, int lkp)
{
    int i = blockIdx.x * 256 + threadIdx.x;  // i = ch*lkp + kp
    int kp = i % lkp;
    int ch = i / lkp;
    int b = ch >> 8, hd = ch & 255;
    bf16 v = __float2bfloat16(0.f);
    if (kp < Lk) v = V[(size_t)kp * vs0 + (size_t)b * vs1 + hd];
    VT[i] = v;
}

// ---------------------------------------------------------------------------
// MFMA flash attention (unchanged; harness-verified).
// ---------------------------------------------------------------------------
__global__ __launch_bounds__(256) void fattn_kernel(
    const bf16* __restrict__ Q, int qs0, int qs1,
    const bf16* __restrict__ K, int ks0, int ks1,
    const bf16* __restrict__ VT, int lkp,
    bf16* __restrict__ O, int Lk, float scale)
{
    const int bh = blockIdx.x;
    const int b = bh >> 3, h = bh & 7;
    const int qt = blockIdx.y;
    const int tid = threadIdx.x;
    const int w = tid >> 6;
    const int lane = tid & 63;
    const int l15 = lane & 15;
    const int quad = lane >> 4;

    __shared__ short Pl[4][16][72];

    const int q0 = qt * 64 + w * 16;
    const int qr = min(q0 + l15, 899);
    short8 aq = *(const short8*)(Q + (size_t)qr * qs0 + (size_t)b * qs1 + h * 32 + quad * 8);

    f32x4 accO0 = {}, accO1 = {};
    float mrow[4] = {-1e30f, -1e30f, -1e30f, -1e30f};
    float lrow[4] = {0.f, 0.f, 0.f, 0.f};

    const bf16* Kb = K + (size_t)b * ks1 + h * 32 + quad * 8;
    const bf16* VTb = VT + (size_t)(b * 256 + h * 32) * lkp;

    const int nkt = (Lk + 63) >> 6;
    for (int kt = 0; kt < nkt; kt++) {
        const int k0 = kt * 64;
        float sv[4][4];
#pragma unroll
        for (int nt = 0; nt < 4; nt++) {
            int kk = k0 + nt * 16 + l15;
            int krow = min(kk, Lk - 1);
            short8 bk = *(const short8*)(Kb + (size_t)krow * ks0);
            f32x4 z = {};
            f32x4 s = __builtin_amdgcn_mfma_f32_16x16x32_bf16(aq, bk, z, 0, 0, 0);
            bool ok = kk < Lk;
#pragma unroll
            for (int r = 0; r < 4; r++) sv[nt][r] = ok ? s[r] * scale : -1e30f;
        }
        float mnew[4], fr[4];
#pragma unroll
        for (int r = 0; r < 4; r++) {
            float t = fmaxf(fmaxf(sv[0][r], sv[1][r]), fmaxf(sv[2][r], sv[3][r]));
            t = fmaxf(t, __shfl_xor(t, 1));
            t = fmaxf(t, __shfl_xor(t, 2));
            t = fmaxf(t, __shfl_xor(t, 4));
            t = fmaxf(t, __shfl_xor(t, 8));
            mnew[r] = fmaxf(mrow[r], t);
            fr[r] = __expf(mrow[r] - mnew[r]);
            mrow[r] = mnew[r];
        }
#pragma unroll
        for (int r = 0; r < 4; r++) {
            float p0 = __expf(sv[0][r] - mnew[r]);
            float p1 = __expf(sv[1][r] - mnew[r]);
            float p2 = __expf(sv[2][r] - mnew[r]);
            float p3 = __expf(sv[3][r] - mnew[r]);
            int row = quad * 4 + r;
            Pl[w][row][l15]      = f2b(p0);
            Pl[w][row][16 + l15] = f2b(p1);
            Pl[w][row][32 + l15] = f2b(p2);
            Pl[w][row][48 + l15] = f2b(p3);
            float t = p0 + p1 + p2 + p3;
            t += __shfl_xor(t, 1);
            t += __shfl_xor(t, 2);
            t += __shfl_xor(t, 4);
            t += __shfl_xor(t, 8);
            lrow[r] = lrow[r] * fr[r] + t;
            accO0[r] *= fr[r];
            accO1[r] *= fr[r];
        }
#pragma unroll
        for (int kt2 = 0; kt2 < 2; kt2++) {
            short8 pa = *(const short8*)&Pl[w][l15][kt2 * 32 + quad * 8];
            short8 v0 = *(const short8*)(VTb + (size_t)l15 * lkp + k0 + kt2 * 32 + quad * 8);
            short8 v1 = *(const short8*)(VTb + (size_t)(16 + l15) * lkp + k0 + kt2 * 32 + quad * 8);
            accO0 = __builtin_amdgcn_mfma_f32_16x16x32_bf16(pa, v0, accO0, 0, 0, 0);
            accO1 = __builtin_amdgcn_mfma_f32_16x16x32_bf16(pa, v1, accO1, 0, 0, 0);
        }
    }
#pragma unroll
    for (int r = 0; r < 4; r++) {
        int q = q0 + quad * 4 + r;
        if (q < 900) {
            float inv = 1.f / lrow[r];
            size_t o = ((size_t)q * 8 + b) * 256 + h * 32;
            O[o + l15]      = __float2bfloat16(accO0[r] * inv);
            O[o + 16 + l15] = __float2bfloat16(accO1[r] * inv);
        }
    }
}

// ---------------------------------------------------------------------------
// Deformable sampling, all batches, 7200 blocks. VAL rows are [ki*8+b][256]
// (row stride 2048 elems per spatial index; +b*256 base).
// ---------------------------------------------------------------------------
__device__ __forceinline__ float sample_one(const bf16* __restrict__ valb,
                                            int base, int HW, int yi, int xi,
                                            int hd32)
{
    bool valid = (xi >= 0) && (xi < HW) && (yi >= 0) && (yi < HW);
    int ix = min(max(xi, 0), HW - 1);
    int iy = min(max(yi, 0), HW - 1);
    size_t idx = (size_t)(base + iy * HW + ix) * 2048 + hd32;
    float v = toF(valb[idx]);
    return valid ? v : 0.f;
}

__global__ __launch_bounds__(256) void deform_kernel(
    const bf16* __restrict__ val,
    const bf16* __restrict__ off,
    const bf16* __restrict__ awl,
    const void* __restrict__ refp,
    bf16* __restrict__ samp, const int* __restrict__ flagp)
{
    const int fl = *flagp;
    const int levH[4] = {128, 64, 32, 16};
    const int levS[4] = {0, 16384, 20480, 21504};
    const int r = blockIdx.x;
    const int tid = threadIdx.x;
    const int h = tid >> 5, d = tid & 31;
    const int hd32 = h * 32 + d;

    const bf16* valb = val + (size_t)(r & 7) * 256;

    const bf16* lg = awl + (size_t)r * 128 + h * 16;
    float w[16];
    float mx = -1e30f;
#pragma unroll
    for (int i = 0; i < 16; i++) { w[i] = toF(lg[i]); mx = fmaxf(mx, w[i]); }
    float sm = 0.f;
#pragma unroll
    for (int i = 0; i < 16; i++) { w[i] = expf(w[i] - mx); sm += w[i]; }
    float inv = 1.f / sm;

    const bf16* offr = off + (size_t)r * 256 + h * 32;
    float acc = 0.f;
#pragma unroll
    for (int l = 0; l < 4; l++) {
        const int HW = levH[l];
        const int base = levS[l];
        float rx = ldF(refp, (size_t)r * 16 + l * 4 + 0, fl);
        float ry = ldF(refp, (size_t)r * 16 + l * 4 + 1, fl);
        float rw = ldF(refp, (size_t)r * 16 + l * 4 + 2, fl);
        float rh = ldF(refp, (size_t)r * 16 + l * 4 + 3, fl);
#pragma unroll
        for (int p = 0; p < 4; p++) {
            float ox = toF(offr[l * 8 + p * 2 + 0]);
            float oy = toF(offr[l * 8 + p * 2 + 1]);
            float locx = rx + ox * 0.125f * rw;   // off/NP * wh * 0.5
            float locy = ry + oy * 0.125f * rh;
            float x = locx * HW - 0.5f;
            float y = locy * HW - 0.5f;
            float x0f = floorf(x), y0f = floorf(y);
            int x0 = (int)x0f, y0 = (int)y0f;
            float fx = x - x0f, fy = y - y0f;
            float wgt = w[l * 4 + p] * inv;
            float s00 = sample_one(valb, base, HW, y0,     x0,     hd32);
            float s01 = sample_one(valb, base, HW, y0,     x0 + 1, hd32);
            float s10 = sample_one(valb, base, HW, y0 + 1, x0,     hd32);
            float s11 = sample_one(valb, base, HW, y0 + 1, x0 + 1, hd32);
            acc += wgt * (s00 * (1.f - fx) * (1.f - fy) + s01 * fx * (1.f - fy) +
                          s10 * (1.f - fx) * fy + s11 * fx * fy);
        }
    }
    samp[(size_t)r * 256 + tid] = __float2bfloat16(acc);
}

// ---------------------------------------------------------------------------
extern "C" void kernel_launch(void* const* d_in, const int* in_sizes, int n_in,
                              void* d_out, int out_size, void* d_ws, size_t ws_size,
                              hipStream_t stream)
{
    (void)in_sizes; (void)n_in;
    const void* tgt      = d_in[0];
    const void* tgt_pos  = d_in[1];
    const void* refp     = d_in[2];
    const void* mem_sup  = d_in[3];
    const void* memory   = d_in[4];
    const void* sa_in_w  = d_in[6];
    const void* sa_in_b  = d_in[7];
    const void* sa_out_w = d_in[8];
    const void* sa_out_b = d_in[9];
    const void* cs_in_w  = d_in[10];
    const void* cs_in_b  = d_in[11];
    const void* cs_out_w = d_in[12];
    const void* cs_out_b = d_in[13];
    const void* so_w = d_in[14];
    const void* so_b = d_in[15];
    const void* aw_w = d_in[16];
    const void* aw_b = d_in[17];
    const void* vp_w = d_in[18];
    const void* vp_b = d_in[19];
    const void* op_w = d_in[20];
    const void* op_b = d_in[21];
    const void* n1w = d_in[22];
    const void* n1b = d_in[23];
    const void* n2w = d_in[24];
    const void* n2b = d_in[25];
    const void* csnw = d_in[26];
    const void* csnb = d_in[27];
    const void* n3w = d_in[28];
    const void* n3b = d_in[29];
    const void* l1w = d_in[30];
    const void* l1b = d_in[31];
    const void* l2w = d_in[32];
    const void* l2b = d_in[33];

    const int S = 900 * 8 * 256;
    const size_t NEEDED = 133496836;
    const dim3 blk(256);
    const dim3 blk2(512);

    if (ws_size < NEEDED) {
        dbg_kernel<<<(out_size + 255) / 256, blk, 0, stream>>>(
            (bf16*)d_out, out_size, (float)(ws_size >> 20));
        return;
    }

    char* base = (char*)d_ws;
    float* T5 = (float*)base;               // [S] f32
    bf16* B1  = (bf16*)(base + 7372800);    // [S]
    bf16* B2  = (bf16*)(base + 11059200);   // [2S]
    bf16* B3  = (bf16*)(base + 18432000);   // [S + 64K elems]
    bf16* B4  = (bf16*)(base + 22249472);   // [S]
    bf16* B5  = (bf16*)(base + 25935872);   // [S]
    bf16* VAL = (bf16*)(base + 29622272);   // [174080 * 256], row = ki*8+b
    bf16* H   = (bf16*)(base + 118751232);  // [7200 * 1024]
    int* FL   = (int*)(base + 133496832);

    const float scale = 0.1767766953f;  // 1/sqrt(32)
    const int MT = 7200;
    const int gy = 113;  // ceil(7200/64)

    detect_kernel<<<1, blk, 0, stream>>>((const unsigned short*)tgt, FL);

    // ---- self attention (Lk=900, LkPad=960; VT in T5 region, dead pre-LN) ----
    mgemm_lds64_kernel<false><<<dim3(4, gy), blk2, 0, stream>>>(
        tgt, 256, 0, 2, tgt_pos, 2, sa_in_w, 0, sa_in_b, 0,
        B2, 512, MT, 256, FL);                                               // q,k (A=tgt+pos)
    mgemm_lds64_kernel<false><<<dim3(2, gy), blk2, 0, stream>>>(
        tgt, 256, 0, 2, nullptr, 0, sa_in_w, 131072, sa_in_b, 512,
        B3, 256, MT, 256, FL);                                               // v
    transpose_v_kernel<<<7680, blk, 0, stream>>>(B3, 2048, 256, (bf16*)T5, 900, 960);
    fattn_kernel<<<dim3(64, 15), blk, 0, stream>>>(
        B2, 4096, 512, B2 + 256, 4096, 512, (bf16*)T5, 960, B4, 900, scale);
    mgemm_lds64_kernel<false><<<dim3(2, gy), blk2, 0, stream>>>(
        B4, 256, 0, 0, nullptr, 0, sa_out_w, 0, sa_out_b, 0,
        B5, 256, MT, 256, FL);
    ln_res_kernel<<<MT, blk, 0, stream>>>(B5, tgt, 2, n2w, n2b, T5, 1, FL);

    // ---- cross attention (memory_support, Lk=100, LkPad=128; VT in B1) ----
    mgemm_lds64_kernel<false><<<dim3(2, gy), blk2, 0, stream>>>(
        T5, 256, 0, 1, tgt_pos, 2, cs_in_w, 0, cs_in_b, 0,
        B2, 256, MT, 256, FL);                                               // q (A=T5+pos)
    mgemm_lds64_kernel<false><<<dim3(4, 13), blk2, 0, stream>>>(
        mem_sup, 256, 0, 2, nullptr, 0, cs_in_w, 65536, cs_in_b, 256,
        B3, 512, 800, 256, FL);                                              // k,v
    transpose_v_kernel<<<1024, blk, 0, stream>>>(B3 + 256, 512, 51200, B1, 100, 128);
    fattn_kernel<<<dim3(64, 15), blk, 0, stream>>>(
        B2, 2048, 256, B3, 512, 51200, B1, 128, B4, 100, scale);
    mgemm_lds64_kernel<false><<<dim3(2, gy), blk2, 0, stream>>>(
        B4, 256, 0, 0, nullptr, 0, cs_out_w, 0, cs_out_b, 0,
        B5, 256, MT, 256, FL);
    ln_res_kernel<<<MT, blk, 0, stream>>>(B5, T5, 1, csnw, csnb, T5, 1, FL);

    // ---- deformable attention (query = T5+pos fused into so/aw A-staging) ----
    mgemm_lds64_kernel<false><<<dim3(2, gy), blk2, 0, stream>>>(
        T5, 256, 0, 1, tgt_pos, 2, so_w, 0, so_b, 0,
        B4, 256, MT, 256, FL);                                               // offsets
    mgemm_lds64_kernel<false><<<dim3(1, gy), blk2, 0, stream>>>(
        T5, 256, 0, 1, tgt_pos, 2, aw_w, 0, aw_b, 0,
        B5, 128, MT, 256, FL);                                               // aw logits
    // val proj: memory as flat [174080][256] rows; VAL rows = ki*8+b
    mgemm_lds_kernel<false><<<dim3(1, 1360), blk2, 0, stream>>>(
        memory, 256, 0, 2, vp_w, 0, vp_b, 0, VAL, 256, 174080, 256, FL);
    deform_kernel<<<7200, blk, 0, stream>>>(VAL, B4, B5, refp, B1, FL);
    mgemm_lds64_kernel<false><<<dim3(2, gy), blk2, 0, stream>>>(
        B1, 256, 0, 0, nullptr, 0, op_w, 0, op_b, 0,
        B5, 256, MT, 256, FL);                                               // out proj
    ln_res_kernel<<<MT, blk, 0, stream>>>(B5, T5, 1, n1w, n1b, T5, 1, FL);

    // ---- FFN (single-shot via H buffer) ----
    mgemm_lds64_kernel<true><<<dim3(8, gy), blk2, 0, stream>>>(
        T5, 256, 0, 1, nullptr, 0, l1w, 0, l1b, 0, H, 1024, MT, 256, FL);
    mgemm_lds64_kernel<false><<<dim3(2, gy), blk2, 0, stream>>>(
        H, 1024, 0, 0, nullptr, 0, l2w, 0, l2b, 0, B5, 256, MT, 1024, FL);
    ln_res_kernel<<<MT, blk, 0, stream>>>(B5, T5, 1, n3w, n3b, d_out, 2, FL);
}